// Round 1
// baseline (2721.326 us; speedup 1.0000x reference)
//
#include <hip/hip_runtime.h>
#include <hip/hip_bf16.h>
#include <math.h>

// Problem constants
constexpr int CB   = 2;      // batch
constexpr int CS   = 4096;   // seq
constexpr int CD   = 1024;   // d_model
constexpr int CH   = 16;     // heads
constexpr int CDH  = 64;     // head dim
constexpr int CR   = 4;      // hash rounds
constexpr int CC   = 64;     // chunk length
constexpr int CNCH = 64;     // num chunks
constexpr int CDFF = 4096;
constexpr int CBS  = CB * CS;        // 8192 rows
constexpr int CBHS = CB * CH * CS;   // 131072

__device__ inline unsigned short f2bf(float f) {
    union { float f; unsigned int u; } a; a.f = f;
    unsigned int u = a.u;
    unsigned int r = (u + 0x7fffu + ((u >> 16) & 1u)) >> 16;
    return (unsigned short)r;
}
__device__ inline float bf2f(unsigned short h) {
    union { float f; unsigned int u; } a; a.u = ((unsigned int)h) << 16; return a.f;
}

// ---------------- LayerNorm: one block per row of D=1024 ----------------
__global__ __launch_bounds__(256) void ln_kernel(const float* __restrict__ x,
        const float* __restrict__ g, const float* __restrict__ bta,
        float* __restrict__ out) {
    int row = blockIdx.x;
    int t = threadIdx.x;
    const float* xr = x + (size_t)row * CD;
    float4 v = *(const float4*)(xr + t * 4);
    float s  = v.x + v.y + v.z + v.w;
    float ss = v.x * v.x + v.y * v.y + v.z * v.z + v.w * v.w;
    #pragma unroll
    for (int off = 1; off < 64; off <<= 1) {
        s  += __shfl_xor(s, off);
        ss += __shfl_xor(ss, off);
    }
    __shared__ float ws_[4], wss_[4];
    int wid = t >> 6;
    if ((t & 63) == 0) { ws_[wid] = s; wss_[wid] = ss; }
    __syncthreads();
    s  = ws_[0] + ws_[1] + ws_[2] + ws_[3];
    ss = wss_[0] + wss_[1] + wss_[2] + wss_[3];
    float mean = s * (1.0f / CD);
    float var  = ss * (1.0f / CD) - mean * mean;
    float rstd = rsqrtf(var + 1e-5f);
    float4 gv = *(const float4*)(g + t * 4);
    float4 bv = *(const float4*)(bta + t * 4);
    float4 o;
    o.x = (v.x - mean) * rstd * gv.x + bv.x;
    o.y = (v.y - mean) * rstd * gv.y + bv.y;
    o.z = (v.z - mean) * rstd * gv.z + bv.z;
    o.w = (v.w - mean) * rstd * gv.w + bv.w;
    *(float4*)(out + (size_t)row * CD + t * 4) = o;
}

// ---------------- fp32 tiled GEMM, 128x128 tile, BK=16 ----------------
// EPI: 0 = none, 1 = bias+relu, 2 = bias+residual, 3 = residual,
//      4 = LSH bucket argmax epilogue (N must be 128, n0 == 0)
template<int EPI>
__global__ __launch_bounds__(256) void gemm_f32(const float* __restrict__ A,
        const float* __restrict__ W, const float* __restrict__ bias,
        const float* __restrict__ res, float* __restrict__ out,
        int M, int N, int K) {
    __shared__ __align__(16) float As[16][132];
    __shared__ __align__(16) float Bs[16][132];
    int tid = threadIdx.x;
    int n0 = blockIdx.x * 128;
    int m0 = blockIdx.y * 128;
    int ty = tid >> 4, tx = tid & 15;
    float acc[8][8];
    #pragma unroll
    for (int i = 0; i < 8; i++)
        #pragma unroll
        for (int j = 0; j < 8; j++) acc[i][j] = 0.f;

    for (int k0 = 0; k0 < K; k0 += 16) {
        #pragma unroll
        for (int it = 0; it < 2; ++it) {
            int f4 = tid + it * 256;         // 0..511, A tile 128x16
            int row = f4 >> 2, c4 = f4 & 3;
            float4 av = *(const float4*)(A + (size_t)(m0 + row) * K + k0 + c4 * 4);
            As[c4 * 4 + 0][row] = av.x;
            As[c4 * 4 + 1][row] = av.y;
            As[c4 * 4 + 2][row] = av.z;
            As[c4 * 4 + 3][row] = av.w;
        }
        #pragma unroll
        for (int it = 0; it < 2; ++it) {
            int f4 = tid + it * 256;         // B tile 16x128
            int kr = f4 >> 5, c4 = f4 & 31;
            *(float4*)(&Bs[kr][c4 * 4]) =
                *(const float4*)(W + (size_t)(k0 + kr) * N + n0 + c4 * 4);
        }
        __syncthreads();
        #pragma unroll
        for (int kk = 0; kk < 16; ++kk) {
            float4 a0 = *(const float4*)(&As[kk][ty * 8]);
            float4 a1 = *(const float4*)(&As[kk][ty * 8 + 4]);
            float4 b0 = *(const float4*)(&Bs[kk][tx * 8]);
            float4 b1 = *(const float4*)(&Bs[kk][tx * 8 + 4]);
            float am[8] = {a0.x, a0.y, a0.z, a0.w, a1.x, a1.y, a1.z, a1.w};
            float bn[8] = {b0.x, b0.y, b0.z, b0.w, b1.x, b1.y, b1.z, b1.w};
            #pragma unroll
            for (int i = 0; i < 8; i++)
                #pragma unroll
                for (int j = 0; j < 8; j++)
                    acc[i][j] = fmaf(am[i], bn[j], acc[i][j]);
        }
        __syncthreads();
    }

    if (EPI == 4) {
        // per-row argmax over concat([row, -row]) for each of R=4 segments of 32
        int* ibuck = (int*)out;
        int q = tx & 3, r = tx >> 2;      // col = r*32 + q*8 + j
        #pragma unroll
        for (int i = 0; i < 8; i++) {
            int m = m0 + ty * 8 + i;
            float bestP = -3.4e38f, bestN = -3.4e38f;
            int biP = 0, biN = 0;
            #pragma unroll
            for (int j = 0; j < 8; j++) {
                float v = acc[i][j];
                if ( v > bestP) { bestP =  v; biP = q * 8 + j; }
                if (-v > bestN) { bestN = -v; biN = q * 8 + j; }
            }
            #pragma unroll
            for (int off = 1; off < 4; off <<= 1) {
                float oP = __shfl_xor(bestP, off); int oiP = __shfl_xor(biP, off);
                float oN = __shfl_xor(bestN, off); int oiN = __shfl_xor(biN, off);
                if (oP > bestP || (oP == bestP && oiP < biP)) { bestP = oP; biP = oiP; }
                if (oN > bestN || (oN == bestN && oiN < biN)) { bestN = oN; biN = oiN; }
            }
            if (q == 0) {
                int bi = (bestP >= bestN) ? biP : (biN + 32);
                int hh = m & 15, ss2 = (m >> 4) & (CS - 1), bb2 = m >> 16;
                ibuck[((size_t)((r * CB + bb2) * CH + hh)) * CS + ss2] = bi;
            }
        }
        return;
    }

    #pragma unroll
    for (int i = 0; i < 8; i++) {
        int m = m0 + ty * 8 + i;
        #pragma unroll
        for (int j4 = 0; j4 < 2; j4++) {
            int n = n0 + tx * 8 + j4 * 4;
            float4 v;
            v.x = acc[i][j4 * 4 + 0]; v.y = acc[i][j4 * 4 + 1];
            v.z = acc[i][j4 * 4 + 2]; v.w = acc[i][j4 * 4 + 3];
            if (EPI == 1 || EPI == 2) {
                float4 bb = *(const float4*)(bias + n);
                v.x += bb.x; v.y += bb.y; v.z += bb.z; v.w += bb.w;
            }
            if (EPI == 1) {
                v.x = fmaxf(v.x, 0.f); v.y = fmaxf(v.y, 0.f);
                v.z = fmaxf(v.z, 0.f); v.w = fmaxf(v.w, 0.f);
            }
            if (EPI == 2 || EPI == 3) {
                float4 rr = *(const float4*)(res + (size_t)m * N + n);
                v.x += rr.x; v.y += rr.y; v.z += rr.z; v.w += rr.w;
            }
            *(float4*)(out + (size_t)m * N + n) = v;
        }
    }
}

// ---------------- stable counting sort per (r,b,h): one wave ----------------
__global__ __launch_bounds__(64) void sort_kernel(const int* __restrict__ buckets,
                                                  int* __restrict__ sorted_pos) {
    int g = blockIdx.x;                  // rbh
    const int* bk = buckets + (size_t)g * CS;
    __shared__ int hist[64][65];
    __shared__ int bstart[64];
    int t = threadIdx.x;                 // 0..63, owns positions t*64..t*64+63
    #pragma unroll
    for (int i = 0; i < 64; i++) hist[t][i] = 0;
    __syncthreads();
    int base = t * 64;
    for (int i = 0; i < 64; i++) { int b = bk[base + i]; hist[t][b]++; }
    __syncthreads();
    // exclusive prefix over threads, per bucket (lane = bucket)
    int run = 0;
    for (int tt = 0; tt < 64; tt++) {
        int c = hist[tt][t];
        hist[tt][t] = run;
        run += c;
    }
    // exclusive prefix over buckets (wave scan)
    int x = run;
    #pragma unroll
    for (int off = 1; off < 64; off <<= 1) {
        int y = __shfl_up(x, off);
        if (t >= off) x += y;
    }
    bstart[t] = x - run;
    __syncthreads();
    for (int i = 0; i < 64; i++) {
        int b = bk[base + i];
        int rank = bstart[b] + hist[t][b];
        hist[t][b]++;
        sorted_pos[(size_t)g * CS + rank] = base + i;
    }
}

// ---------------- chunked LSH attention: one block per (r,b,h,chunk) --------
__global__ __launch_bounds__(256) void attn_kernel(const float* __restrict__ qkbuf,
        const float* __restrict__ vbuf, const int* __restrict__ buckets,
        const int* __restrict__ sorted, unsigned short* __restrict__ o_all,
        float* __restrict__ l_all) {
    int n  = blockIdx.x;                 // chunk
    int r  = blockIdx.y;
    int bh = blockIdx.z;
    int b = bh >> 4, h = bh & 15;
    int rbh = (r * CB + b) * CH + h;
    int tid = threadIdx.x;

    __shared__ __align__(16) float smKV[64 * 136];  // kT[d][kk] (stride 136) -> vS[kk][d] (stride 68)
    __shared__ __align__(16) float smQP[64 * 68];   // qT[d][m]  (stride 68)  -> pT ushort[kk][m] (stride 68)
    __shared__ int pk[128];
    __shared__ int bkk[128];

    int prev = (n + CNCH - 1) & (CNCH - 1);
    if (tid < 128) {
        int i = tid & 63;
        int ch = (tid < 64) ? n : prev;
        int p = sorted[(size_t)rbh * CS + ch * CC + i];
        pk[tid] = p;
        bkk[tid] = buckets[(size_t)rbh * CS + p];
    }
    __syncthreads();

    // stage raw qk rows (128 rows x 64) transposed into kT
    #pragma unroll
    for (int it = 0; it < 8; ++it) {
        int f4 = tid + it * 256;             // 0..2047
        int kk = f4 >> 4, d4 = f4 & 15;
        float4 v = *(const float4*)(qkbuf + ((size_t)(b * CS + pk[kk])) * CD + h * 64 + d4 * 4);
        smKV[(d4 * 4 + 0) * 136 + kk] = v.x;
        smKV[(d4 * 4 + 1) * 136 + kk] = v.y;
        smKV[(d4 * 4 + 2) * 136 + kk] = v.z;
        smKV[(d4 * 4 + 3) * 136 + kk] = v.w;
    }
    __syncthreads();
    // copy raw q (first 64 cols) into qT
    #pragma unroll
    for (int it = 0; it < 16; ++it) {
        int idx = tid + it * 256;            // 0..4095
        int d = idx >> 6, m = idx & 63;
        smQP[d * 68 + m] = smKV[d * 136 + m];
    }
    __syncthreads();
    // L2-normalize key columns
    if (tid < 128) {
        float ssum = 0.f;
        for (int d = 0; d < 64; ++d) { float x = smKV[d * 136 + tid]; ssum += x * x; }
        float rn = 1.f / (sqrtf(ssum) + 1e-6f);
        for (int d = 0; d < 64; ++d) smKV[d * 136 + tid] *= rn;
    }
    __syncthreads();

    // scores: thread (ty,tx) -> rows ty*4..+3, keys tx*8..+7
    int ty = tid >> 4, tx = tid & 15;
    float sc[4][8];
    #pragma unroll
    for (int i = 0; i < 4; i++)
        #pragma unroll
        for (int j = 0; j < 8; j++) sc[i][j] = 0.f;
    for (int d = 0; d < 64; ++d) {
        float4 qv = *(const float4*)&smQP[d * 68 + ty * 4];
        float4 k0 = *(const float4*)&smKV[d * 136 + tx * 8];
        float4 k1 = *(const float4*)&smKV[d * 136 + tx * 8 + 4];
        float qa[4] = {qv.x, qv.y, qv.z, qv.w};
        float kb[8] = {k0.x, k0.y, k0.z, k0.w, k1.x, k1.y, k1.z, k1.w};
        #pragma unroll
        for (int i = 0; i < 4; i++)
            #pragma unroll
            for (int j = 0; j < 8; j++)
                sc[i][j] = fmaf(qa[i], kb[j], sc[i][j]);
    }
    // scale + masks
    #pragma unroll
    for (int i = 0; i < 4; i++) {
        int mi = ty * 4 + i;
        int bq = bkk[mi], pq = pk[mi];
        #pragma unroll
        for (int j = 0; j < 8; j++) {
            int kkj = tx * 8 + j;
            float v = sc[i][j] * 0.125f;
            if (bq != bkk[kkj]) v = -1e9f;
            if (pq == pk[kkj]) v = -1e5f;
            sc[i][j] = v;
        }
    }
    // row softmax (reduce across 16 tx lanes)
    float mx[4], sm[4];
    #pragma unroll
    for (int i = 0; i < 4; i++) {
        float m_ = sc[i][0];
        #pragma unroll
        for (int j = 1; j < 8; j++) m_ = fmaxf(m_, sc[i][j]);
        #pragma unroll
        for (int off = 1; off < 16; off <<= 1) m_ = fmaxf(m_, __shfl_xor(m_, off));
        mx[i] = m_;
        float s_ = 0.f;
        #pragma unroll
        for (int j = 0; j < 8; j++) { sc[i][j] = expf(sc[i][j] - m_); s_ += sc[i][j]; }
        #pragma unroll
        for (int off = 1; off < 16; off <<= 1) s_ += __shfl_xor(s_, off);
        sm[i] = s_;
    }
    if (tx == 0) {
        #pragma unroll
        for (int i = 0; i < 4; i++)
            l_all[(size_t)rbh * CS + pk[ty * 4 + i]] = mx[i] + logf(sm[i]);
    }
    __syncthreads();   // qT/kT reads done; safe to overwrite

    // write normalized probs (bf16) into pT; load V into smKV
    unsigned short* pT = (unsigned short*)smQP;
    #pragma unroll
    for (int j = 0; j < 8; j++) {
        ushort4 w;
        w.x = f2bf(sc[0][j] / sm[0]);
        w.y = f2bf(sc[1][j] / sm[1]);
        w.z = f2bf(sc[2][j] / sm[2]);
        w.w = f2bf(sc[3][j] / sm[3]);
        *(ushort4*)&pT[(tx * 8 + j) * 68 + ty * 4] = w;
    }
    #pragma unroll
    for (int it = 0; it < 8; ++it) {
        int f4 = tid + it * 256;
        int kk = f4 >> 4, d4 = f4 & 15;
        float4 v = *(const float4*)(vbuf + ((size_t)(b * CS + pk[kk])) * CD + h * 64 + d4 * 4);
        *(float4*)&smKV[kk * 68 + d4 * 4] = v;
    }
    __syncthreads();

    // PV: thread (ty,tx) -> rows ty*4..+3, dims tx*4..+3
    float o[4][4];
    #pragma unroll
    for (int i = 0; i < 4; i++)
        #pragma unroll
        for (int j = 0; j < 4; j++) o[i][j] = 0.f;
    for (int kk = 0; kk < 128; ++kk) {
        ushort4 pu = *(ushort4*)&pT[kk * 68 + ty * 4];
        float4 vv = *(float4*)&smKV[kk * 68 + tx * 4];
        float pa[4] = {bf2f(pu.x), bf2f(pu.y), bf2f(pu.z), bf2f(pu.w)};
        float vb[4] = {vv.x, vv.y, vv.z, vv.w};
        #pragma unroll
        for (int i = 0; i < 4; i++)
            #pragma unroll
            for (int j = 0; j < 4; j++)
                o[i][j] = fmaf(pa[i], vb[j], o[i][j]);
    }
    #pragma unroll
    for (int i = 0; i < 4; i++) {
        int pos = pk[ty * 4 + i];
        ushort4 w;
        w.x = f2bf(o[i][0]); w.y = f2bf(o[i][1]);
        w.z = f2bf(o[i][2]); w.w = f2bf(o[i][3]);
        *(ushort4*)&o_all[((size_t)rbh * CS + pos) * CDH + tx * 4] = w;
    }
}

// ---------------- combine rounds: softmax over R of logsumexp ----------------
__global__ __launch_bounds__(256) void combine_kernel(const unsigned short* __restrict__ o_all,
        const float* __restrict__ l_all, float* __restrict__ attnout) {
    int idx = blockIdx.x * 256 + threadIdx.x;     // over BHS*DH
    int d = idx & 63, bhs = idx >> 6;
    int s2 = bhs & (CS - 1), bh = bhs >> 12, h = bh & 15, b = bh >> 4;
    float lr[4];
    #pragma unroll
    for (int r = 0; r < CR; r++) lr[r] = l_all[(size_t)r * CBHS + bhs];
    float m = fmaxf(fmaxf(lr[0], lr[1]), fmaxf(lr[2], lr[3]));
    float w[4], sum = 0.f;
    #pragma unroll
    for (int r = 0; r < CR; r++) { w[r] = expf(lr[r] - m); sum += w[r]; }
    float acc = 0.f;
    #pragma unroll
    for (int r = 0; r < CR; r++)
        acc += w[r] * bf2f(o_all[((size_t)r * CBHS + bhs) * CDH + d]);
    acc /= sum;
    attnout[((size_t)(b * CS + s2)) * CD + h * 64 + d] = acc;
}

extern "C" void kernel_launch(void* const* d_in, const int* in_sizes, int n_in,
                              void* d_out, int out_size, void* d_ws, size_t ws_size,
                              hipStream_t stream) {
    const float* x1   = (const float*)d_in[0];
    const float* x2   = (const float*)d_in[1];
    const float* Wqk  = (const float*)d_in[2];
    const float* Wv   = (const float*)d_in[3];
    const float* Wo   = (const float*)d_in[4];
    const float* ln1g = (const float*)d_in[5];
    const float* ln1b = (const float*)d_in[6];
    const float* W1   = (const float*)d_in[7];
    const float* bf1  = (const float*)d_in[8];
    const float* W2   = (const float*)d_in[9];
    const float* bf2  = (const float*)d_in[10];
    const float* ln2g = (const float*)d_in[11];
    const float* ln2b = (const float*)d_in[12];
    const float* rot  = (const float*)d_in[13];   // [64][4][32] == [64][128] row-major

    float* bufA = (float*)d_ws;                              // ln2 / attnout / ln_y1
    float* bufB = bufA + (size_t)CBS * CD;                   // qk ; later ffh start
    float* bufC = bufB + (size_t)CBS * CD;                   // v
    unsigned short* o_all = (unsigned short*)(bufC + (size_t)CBS * CD); // bf16, 33.5M elems
    float* l_all  = (float*)(o_all + (size_t)CR * CBHS * CDH);
    int* buckets  = (int*)(l_all + (size_t)CR * CBHS);
    int* sorted   = buckets + (size_t)CR * CBHS;
    float* ffh = bufB;                                       // aliases B+C+o_all = 134 MB
    float* y1 = (float*)d_out;
    float* y2 = y1 + (size_t)CBS * CD;

    // 1. ln(x2)
    ln_kernel<<<CBS, 256, 0, stream>>>(x2, ln1g, ln1b, bufA);
    // 2. qk / v projections (fp32 — qk feeds bucketing, must stay fp32)
    gemm_f32<0><<<dim3(CD / 128, CBS / 128), 256, 0, stream>>>(bufA, Wqk, nullptr, nullptr, bufB, CBS, CD, CD);
    gemm_f32<0><<<dim3(CD / 128, CBS / 128), 256, 0, stream>>>(bufA, Wv, nullptr, nullptr, bufC, CBS, CD, CD);
    // 3. LSH rotation GEMM + fused argmax -> buckets  (qk viewed [131072,64] @ rot [64,128])
    gemm_f32<4><<<dim3(1, CBHS / 128), 256, 0, stream>>>(bufB, rot, nullptr, nullptr, (float*)buckets, CBHS, 128, 64);
    // 4. stable counting sort per (r,b,h)
    sort_kernel<<<CR * CB * CH, 64, 0, stream>>>(buckets, sorted);
    // 5. chunked masked attention
    attn_kernel<<<dim3(CNCH, CR, CB * CH), 256, 0, stream>>>(bufB, bufC, buckets, sorted, o_all, l_all);
    // 6. round-weighted combine -> attnout (bufA reusable: ln2 dead)
    combine_kernel<<<(CBHS * CDH) / 256, 256, 0, stream>>>(o_all, l_all, bufA);
    // 7. y1 = attnout @ Wo + x1
    gemm_f32<3><<<dim3(CD / 128, CBS / 128), 256, 0, stream>>>(bufA, Wo, nullptr, x1, y1, CBS, CD, CD);
    // 8. ln(y1)
    ln_kernel<<<CBS, 256, 0, stream>>>(y1, ln2g, ln2b, bufA);
    // 9. ffh = relu(ln_y1 @ W1 + bf1)
    gemm_f32<1><<<dim3(CDFF / 128, CBS / 128), 256, 0, stream>>>(bufA, W1, bf1, nullptr, ffh, CBS, CDFF, CD);
    // 10. y2 = ffh @ W2 + bf2 + x2
    gemm_f32<2><<<dim3(CD / 128, CBS / 128), 256, 0, stream>>>(ffh, W2, bf2, x2, y2, CBS, CD, CDFF);
}

// Round 2
// 1033.614 us; speedup vs baseline: 2.6328x; 2.6328x over previous
//
#include <hip/hip_runtime.h>
#include <hip/hip_bf16.h>
#include <math.h>

// Problem constants
constexpr int CB   = 2;      // batch
constexpr int CS   = 4096;   // seq
constexpr int CD   = 1024;   // d_model
constexpr int CH   = 16;     // heads
constexpr int CDH  = 64;     // head dim
constexpr int CR   = 4;      // hash rounds
constexpr int CC   = 64;     // chunk length
constexpr int CNCH = 64;     // num chunks
constexpr int CDFF = 4096;
constexpr int CBS  = CB * CS;        // 8192 rows
constexpr int CBHS = CB * CH * CS;   // 131072

typedef __attribute__((ext_vector_type(8))) short short8;
typedef __attribute__((ext_vector_type(4))) float f32x4;

__device__ inline unsigned short f2bf(float f) {
    union { float f; unsigned int u; } a; a.f = f;
    unsigned int u = a.u;
    unsigned int r = (u + 0x7fffu + ((u >> 16) & 1u)) >> 16;
    return (unsigned short)r;
}
__device__ inline float bf2f(unsigned short h) {
    union { float f; unsigned int u; } a; a.u = ((unsigned int)h) << 16; return a.f;
}

#define AS3 __attribute__((address_space(3)))
#define AS1 __attribute__((address_space(1)))
__device__ inline void gload16(const unsigned short* g, unsigned short* l) {
    __builtin_amdgcn_global_load_lds((const AS1 unsigned int*)g,
                                     (AS3 unsigned int*)l, 16, 0, 0);
}

// ---------------- LayerNorm: one block per row of D=1024; fp32 + bf16 out ----
__global__ __launch_bounds__(256) void ln_kernel(const float* __restrict__ x,
        const float* __restrict__ g, const float* __restrict__ bta,
        float* __restrict__ out, unsigned short* __restrict__ out16) {
    int row = blockIdx.x;
    int t = threadIdx.x;
    const float* xr = x + (size_t)row * CD;
    float4 v = *(const float4*)(xr + t * 4);
    float s  = v.x + v.y + v.z + v.w;
    float ss = v.x * v.x + v.y * v.y + v.z * v.z + v.w * v.w;
    #pragma unroll
    for (int off = 1; off < 64; off <<= 1) {
        s  += __shfl_xor(s, off);
        ss += __shfl_xor(ss, off);
    }
    __shared__ float ws_[4], wss_[4];
    int wid = t >> 6;
    if ((t & 63) == 0) { ws_[wid] = s; wss_[wid] = ss; }
    __syncthreads();
    s  = ws_[0] + ws_[1] + ws_[2] + ws_[3];
    ss = wss_[0] + wss_[1] + wss_[2] + wss_[3];
    float mean = s * (1.0f / CD);
    float var  = ss * (1.0f / CD) - mean * mean;
    float rstd = rsqrtf(var + 1e-5f);
    float4 gv = *(const float4*)(g + t * 4);
    float4 bv = *(const float4*)(bta + t * 4);
    float4 o;
    o.x = (v.x - mean) * rstd * gv.x + bv.x;
    o.y = (v.y - mean) * rstd * gv.y + bv.y;
    o.z = (v.z - mean) * rstd * gv.z + bv.z;
    o.w = (v.w - mean) * rstd * gv.w + bv.w;
    if (out) *(float4*)(out + (size_t)row * CD + t * 4) = o;
    if (out16) {
        ushort4 h; h.x = f2bf(o.x); h.y = f2bf(o.y); h.z = f2bf(o.z); h.w = f2bf(o.w);
        *(ushort4*)(out16 + (size_t)row * CD + t * 4) = h;
    }
}

// ---------------- weight transpose + fp32->bf16: W[K][N] -> WT[N][K] --------
__global__ __launch_bounds__(256) void wtrans_kernel(const float* __restrict__ W,
        unsigned short* __restrict__ WT, int K, int N) {
    __shared__ float tile[64][65];
    int n0 = blockIdx.x * 64, k0 = blockIdx.y * 64;
    int tid = threadIdx.x;
    int r = tid >> 4, c4 = tid & 15;
    #pragma unroll
    for (int it = 0; it < 4; ++it) {
        int row = r + it * 16;
        float4 v = *(const float4*)(W + (size_t)(k0 + row) * N + n0 + c4 * 4);
        tile[row][c4 * 4 + 0] = v.x; tile[row][c4 * 4 + 1] = v.y;
        tile[row][c4 * 4 + 2] = v.z; tile[row][c4 * 4 + 3] = v.w;
    }
    __syncthreads();
    #pragma unroll
    for (int it = 0; it < 4; ++it) {
        int nrow = r + it * 16;
        ushort4 h;
        h.x = f2bf(tile[c4 * 4 + 0][nrow]);
        h.y = f2bf(tile[c4 * 4 + 1][nrow]);
        h.z = f2bf(tile[c4 * 4 + 2][nrow]);
        h.w = f2bf(tile[c4 * 4 + 3][nrow]);
        *(ushort4*)(WT + (size_t)(n0 + nrow) * K + k0 + c4 * 4) = h;
    }
}

// ---------------- bf16 MFMA GEMM: C[M][N] = A[M][K] @ BT[N][K]^T ------------
// m97-style: 128x128 tile, BK=32, 4 waves, 4x4 16x16x32 MFMA per wave.
// XOR chunk swizzle: LDS cell [R][p] holds global k-chunk p ^ ((R>>1)&3).
// EPI: 0 = fp32 out; 1 = bias+relu -> bf16 out; 2 = bias+residual -> fp32;
//      3 = residual -> fp32
template<int EPI>
__global__ __launch_bounds__(256) void gemm_bf16(const unsigned short* __restrict__ A,
        const unsigned short* __restrict__ BT, const float* __restrict__ bias,
        const float* __restrict__ res, void* __restrict__ outp,
        int M, int N, int K) {
    __shared__ __align__(16) unsigned short As[128 * 32];
    __shared__ __align__(16) unsigned short Bs[128 * 32];
    int tid = threadIdx.x;
    int w = tid >> 6, l = tid & 63;
    int m0 = blockIdx.y * 128, n0 = blockIdx.x * 128;
    int wm = (w >> 1) * 64, wn = (w & 1) * 64;

    // staging source pointers (advance by k0 each iter)
    const unsigned short* gA[2]; const unsigned short* gB[2];
    unsigned short* ldsA[2]; unsigned short* ldsB[2];
    int gchunk = (l & 3) ^ ((l >> 3) & 3);
    #pragma unroll
    for (int s = 0; s < 2; ++s) {
        int j = w * 2 + s;
        int R = j * 16 + (l >> 2);
        gA[s] = A + (size_t)(m0 + R) * K + gchunk * 8;
        gB[s] = BT + (size_t)(n0 + R) * K + gchunk * 8;
        ldsA[s] = As + j * 512;
        ldsB[s] = Bs + j * 512;
    }
    // fragment LDS offsets (shorts); p = (l>>4) ^ ((l>>1)&3)
    int p = (l >> 4) ^ (((l & 15) >> 1) & 3);
    int aoff = (wm + (l & 15)) * 32 + p * 8;
    int boff = (wn + (l & 15)) * 32 + p * 8;

    f32x4 acc[4][4];
    #pragma unroll
    for (int i = 0; i < 4; i++)
        #pragma unroll
        for (int j = 0; j < 4; j++) acc[i][j] = (f32x4)(0.f);

    for (int k0 = 0; k0 < K; k0 += 32) {
        gload16(gA[0] + k0, ldsA[0]);
        gload16(gA[1] + k0, ldsA[1]);
        gload16(gB[0] + k0, ldsB[0]);
        gload16(gB[1] + k0, ldsB[1]);
        __syncthreads();
        short8 af[4], bf[4];
        #pragma unroll
        for (int im = 0; im < 4; ++im) af[im] = *(const short8*)(As + aoff + im * 512);
        #pragma unroll
        for (int in = 0; in < 4; ++in) bf[in] = *(const short8*)(Bs + boff + in * 512);
        #pragma unroll
        for (int im = 0; im < 4; ++im)
            #pragma unroll
            for (int in = 0; in < 4; ++in)
                acc[im][in] = __builtin_amdgcn_mfma_f32_16x16x32_bf16(
                    af[im], bf[in], acc[im][in], 0, 0, 0);
        __syncthreads();
    }

    // epilogue: lane l, reg r -> m = wm+im*16+(l>>4)*4+r, n = wn+in*16+(l&15)
    float bv[4];
    if (EPI == 1 || EPI == 2) {
        #pragma unroll
        for (int in = 0; in < 4; ++in) bv[in] = bias[n0 + wn + in * 16 + (l & 15)];
    }
    #pragma unroll
    for (int im = 0; im < 4; ++im) {
        #pragma unroll
        for (int in = 0; in < 4; ++in) {
            int n = n0 + wn + in * 16 + (l & 15);
            #pragma unroll
            for (int r = 0; r < 4; ++r) {
                int m = m0 + wm + im * 16 + (l >> 4) * 4 + r;
                float v = acc[im][in][r];
                if (EPI == 1) {
                    v = fmaxf(v + bv[in], 0.f);
                    ((unsigned short*)outp)[(size_t)m * N + n] = f2bf(v);
                } else {
                    if (EPI == 2) v += bv[in] + res[(size_t)m * N + n];
                    if (EPI == 3) v += res[(size_t)m * N + n];
                    ((float*)outp)[(size_t)m * N + n] = v;
                }
            }
        }
    }
}

// ---------------- fp32 tiled GEMM (bucket path only) ----------------
// EPI: 0 = none, 4 = LSH bucket argmax epilogue (N must be 128, n0 == 0)
template<int EPI>
__global__ __launch_bounds__(256) void gemm_f32(const float* __restrict__ A,
        const float* __restrict__ W, float* __restrict__ out,
        int M, int N, int K) {
    __shared__ __align__(16) float As[16][132];
    __shared__ __align__(16) float Bs[16][132];
    int tid = threadIdx.x;
    int n0 = blockIdx.x * 128;
    int m0 = blockIdx.y * 128;
    int ty = tid >> 4, tx = tid & 15;
    float acc[8][8];
    #pragma unroll
    for (int i = 0; i < 8; i++)
        #pragma unroll
        for (int j = 0; j < 8; j++) acc[i][j] = 0.f;

    for (int k0 = 0; k0 < K; k0 += 16) {
        #pragma unroll
        for (int it = 0; it < 2; ++it) {
            int f4 = tid + it * 256;
            int row = f4 >> 2, c4 = f4 & 3;
            float4 av = *(const float4*)(A + (size_t)(m0 + row) * K + k0 + c4 * 4);
            As[c4 * 4 + 0][row] = av.x;
            As[c4 * 4 + 1][row] = av.y;
            As[c4 * 4 + 2][row] = av.z;
            As[c4 * 4 + 3][row] = av.w;
        }
        #pragma unroll
        for (int it = 0; it < 2; ++it) {
            int f4 = tid + it * 256;
            int kr = f4 >> 5, c4 = f4 & 31;
            *(float4*)(&Bs[kr][c4 * 4]) =
                *(const float4*)(W + (size_t)(k0 + kr) * N + n0 + c4 * 4);
        }
        __syncthreads();
        #pragma unroll
        for (int kk = 0; kk < 16; ++kk) {
            float4 a0 = *(const float4*)(&As[kk][ty * 8]);
            float4 a1 = *(const float4*)(&As[kk][ty * 8 + 4]);
            float4 b0 = *(const float4*)(&Bs[kk][tx * 8]);
            float4 b1 = *(const float4*)(&Bs[kk][tx * 8 + 4]);
            float am[8] = {a0.x, a0.y, a0.z, a0.w, a1.x, a1.y, a1.z, a1.w};
            float bn[8] = {b0.x, b0.y, b0.z, b0.w, b1.x, b1.y, b1.z, b1.w};
            #pragma unroll
            for (int i = 0; i < 8; i++)
                #pragma unroll
                for (int j = 0; j < 8; j++)
                    acc[i][j] = fmaf(am[i], bn[j], acc[i][j]);
        }
        __syncthreads();
    }

    if (EPI == 4) {
        int* ibuck = (int*)out;
        int q = tx & 3, r = tx >> 2;      // col = r*32 + q*8 + j
        #pragma unroll
        for (int i = 0; i < 8; i++) {
            int m = m0 + ty * 8 + i;
            float bestP = -3.4e38f, bestN = -3.4e38f;
            int biP = 0, biN = 0;
            #pragma unroll
            for (int j = 0; j < 8; j++) {
                float v = acc[i][j];
                if ( v > bestP) { bestP =  v; biP = q * 8 + j; }
                if (-v > bestN) { bestN = -v; biN = q * 8 + j; }
            }
            #pragma unroll
            for (int off = 1; off < 4; off <<= 1) {
                float oP = __shfl_xor(bestP, off); int oiP = __shfl_xor(biP, off);
                float oN = __shfl_xor(bestN, off); int oiN = __shfl_xor(biN, off);
                if (oP > bestP || (oP == bestP && oiP < biP)) { bestP = oP; biP = oiP; }
                if (oN > bestN || (oN == bestN && oiN < biN)) { bestN = oN; biN = oiN; }
            }
            if (q == 0) {
                int bi = (bestP >= bestN) ? biP : (biN + 32);
                int hh = m & 15, ss2 = (m >> 4) & (CS - 1), bb2 = m >> 16;
                ibuck[((size_t)((r * CB + bb2) * CH + hh)) * CS + ss2] = bi;
            }
        }
        return;
    }

    #pragma unroll
    for (int i = 0; i < 8; i++) {
        int m = m0 + ty * 8 + i;
        #pragma unroll
        for (int j4 = 0; j4 < 2; j4++) {
            int n = n0 + tx * 8 + j4 * 4;
            float4 v;
            v.x = acc[i][j4 * 4 + 0]; v.y = acc[i][j4 * 4 + 1];
            v.z = acc[i][j4 * 4 + 2]; v.w = acc[i][j4 * 4 + 3];
            *(float4*)(out + (size_t)m * N + n) = v;
        }
    }
}

// ---------------- stable counting sort per (r,b,h): one wave ----------------
__global__ __launch_bounds__(64) void sort_kernel(const int* __restrict__ buckets,
                                                  int* __restrict__ sorted_pos) {
    int g = blockIdx.x;                  // rbh
    const int* bk = buckets + (size_t)g * CS;
    __shared__ int hist[64][65];
    __shared__ int bstart[64];
    int t = threadIdx.x;
    #pragma unroll
    for (int i = 0; i < 64; i++) hist[t][i] = 0;
    __syncthreads();
    int base = t * 64;
    for (int i = 0; i < 64; i++) { int b = bk[base + i]; hist[t][b]++; }
    __syncthreads();
    int run = 0;
    for (int tt = 0; tt < 64; tt++) {
        int c = hist[tt][t];
        hist[tt][t] = run;
        run += c;
    }
    int x = run;
    #pragma unroll
    for (int off = 1; off < 64; off <<= 1) {
        int y = __shfl_up(x, off);
        if (t >= off) x += y;
    }
    bstart[t] = x - run;
    __syncthreads();
    for (int i = 0; i < 64; i++) {
        int b = bk[base + i];
        int rank = bstart[b] + hist[t][b];
        hist[t][b]++;
        sorted_pos[(size_t)g * CS + rank] = base + i;
    }
}

// ---------------- chunked LSH attention: one block per (r,b,h,chunk) --------
__global__ __launch_bounds__(256) void attn_kernel(const float* __restrict__ qkbuf,
        const float* __restrict__ vbuf, const int* __restrict__ buckets,
        const int* __restrict__ sorted, unsigned short* __restrict__ o_all,
        float* __restrict__ l_all) {
    int n  = blockIdx.x;
    int r  = blockIdx.y;
    int bh = blockIdx.z;
    int b = bh >> 4, h = bh & 15;
    int rbh = (r * CB + b) * CH + h;
    int tid = threadIdx.x;

    __shared__ __align__(16) float smKV[64 * 136];
    __shared__ __align__(16) float smQP[64 * 68];
    __shared__ int pk[128];
    __shared__ int bkk[128];

    int prev = (n + CNCH - 1) & (CNCH - 1);
    if (tid < 128) {
        int i = tid & 63;
        int ch = (tid < 64) ? n : prev;
        int p = sorted[(size_t)rbh * CS + ch * CC + i];
        pk[tid] = p;
        bkk[tid] = buckets[(size_t)rbh * CS + p];
    }
    __syncthreads();

    #pragma unroll
    for (int it = 0; it < 8; ++it) {
        int f4 = tid + it * 256;
        int kk = f4 >> 4, d4 = f4 & 15;
        float4 v = *(const float4*)(qkbuf + ((size_t)(b * CS + pk[kk])) * CD + h * 64 + d4 * 4);
        smKV[(d4 * 4 + 0) * 136 + kk] = v.x;
        smKV[(d4 * 4 + 1) * 136 + kk] = v.y;
        smKV[(d4 * 4 + 2) * 136 + kk] = v.z;
        smKV[(d4 * 4 + 3) * 136 + kk] = v.w;
    }
    __syncthreads();
    #pragma unroll
    for (int it = 0; it < 16; ++it) {
        int idx = tid + it * 256;
        int d = idx >> 6, m = idx & 63;
        smQP[d * 68 + m] = smKV[d * 136 + m];
    }
    __syncthreads();
    if (tid < 128) {
        float ssum = 0.f;
        for (int d = 0; d < 64; ++d) { float x = smKV[d * 136 + tid]; ssum += x * x; }
        float rn = 1.f / (sqrtf(ssum) + 1e-6f);
        for (int d = 0; d < 64; ++d) smKV[d * 136 + tid] *= rn;
    }
    __syncthreads();

    int ty = tid >> 4, tx = tid & 15;
    float sc[4][8];
    #pragma unroll
    for (int i = 0; i < 4; i++)
        #pragma unroll
        for (int j = 0; j < 8; j++) sc[i][j] = 0.f;
    for (int d = 0; d < 64; ++d) {
        float4 qv = *(const float4*)&smQP[d * 68 + ty * 4];
        float4 k0 = *(const float4*)&smKV[d * 136 + tx * 8];
        float4 k1 = *(const float4*)&smKV[d * 136 + tx * 8 + 4];
        float qa[4] = {qv.x, qv.y, qv.z, qv.w};
        float kb[8] = {k0.x, k0.y, k0.z, k0.w, k1.x, k1.y, k1.z, k1.w};
        #pragma unroll
        for (int i = 0; i < 4; i++)
            #pragma unroll
            for (int j = 0; j < 8; j++)
                sc[i][j] = fmaf(qa[i], kb[j], sc[i][j]);
    }
    #pragma unroll
    for (int i = 0; i < 4; i++) {
        int mi = ty * 4 + i;
        int bq = bkk[mi], pq = pk[mi];
        #pragma unroll
        for (int j = 0; j < 8; j++) {
            int kkj = tx * 8 + j;
            float v = sc[i][j] * 0.125f;
            if (bq != bkk[kkj]) v = -1e9f;
            if (pq == pk[kkj]) v = -1e5f;
            sc[i][j] = v;
        }
    }
    float mx[4], sm[4];
    #pragma unroll
    for (int i = 0; i < 4; i++) {
        float m_ = sc[i][0];
        #pragma unroll
        for (int j = 1; j < 8; j++) m_ = fmaxf(m_, sc[i][j]);
        #pragma unroll
        for (int off = 1; off < 16; off <<= 1) m_ = fmaxf(m_, __shfl_xor(m_, off));
        mx[i] = m_;
        float s_ = 0.f;
        #pragma unroll
        for (int j = 0; j < 8; j++) { sc[i][j] = expf(sc[i][j] - m_); s_ += sc[i][j]; }
        #pragma unroll
        for (int off = 1; off < 16; off <<= 1) s_ += __shfl_xor(s_, off);
        sm[i] = s_;
    }
    if (tx == 0) {
        #pragma unroll
        for (int i = 0; i < 4; i++)
            l_all[(size_t)rbh * CS + pk[ty * 4 + i]] = mx[i] + logf(sm[i]);
    }
    __syncthreads();

    unsigned short* pT = (unsigned short*)smQP;
    #pragma unroll
    for (int j = 0; j < 8; j++) {
        ushort4 w;
        w.x = f2bf(sc[0][j] / sm[0]);
        w.y = f2bf(sc[1][j] / sm[1]);
        w.z = f2bf(sc[2][j] / sm[2]);
        w.w = f2bf(sc[3][j] / sm[3]);
        *(ushort4*)&pT[(tx * 8 + j) * 68 + ty * 4] = w;
    }
    #pragma unroll
    for (int it = 0; it < 8; ++it) {
        int f4 = tid + it * 256;
        int kk = f4 >> 4, d4 = f4 & 15;
        float4 v = *(const float4*)(vbuf + ((size_t)(b * CS + pk[kk])) * CD + h * 64 + d4 * 4);
        *(float4*)&smKV[kk * 68 + d4 * 4] = v;
    }
    __syncthreads();

    float o[4][4];
    #pragma unroll
    for (int i = 0; i < 4; i++)
        #pragma unroll
        for (int j = 0; j < 4; j++) o[i][j] = 0.f;
    for (int kk = 0; kk < 128; ++kk) {
        ushort4 pu = *(ushort4*)&pT[kk * 68 + ty * 4];
        float4 vv = *(float4*)&smKV[kk * 68 + tx * 4];
        float pa[4] = {bf2f(pu.x), bf2f(pu.y), bf2f(pu.z), bf2f(pu.w)};
        float vb[4] = {vv.x, vv.y, vv.z, vv.w};
        #pragma unroll
        for (int i = 0; i < 4; i++)
            #pragma unroll
            for (int j = 0; j < 4; j++)
                o[i][j] = fmaf(pa[i], vb[j], o[i][j]);
    }
    #pragma unroll
    for (int i = 0; i < 4; i++) {
        int pos = pk[ty * 4 + i];
        ushort4 w;
        w.x = f2bf(o[i][0]); w.y = f2bf(o[i][1]);
        w.z = f2bf(o[i][2]); w.w = f2bf(o[i][3]);
        *(ushort4*)&o_all[((size_t)rbh * CS + pos) * CDH + tx * 4] = w;
    }
}

// ---------------- combine rounds: softmax over R of logsumexp; bf16 out -----
__global__ __launch_bounds__(256) void combine_kernel(const unsigned short* __restrict__ o_all,
        const float* __restrict__ l_all, unsigned short* __restrict__ attnout16) {
    int idx = blockIdx.x * 256 + threadIdx.x;
    int d = idx & 63, bhs = idx >> 6;
    int s2 = bhs & (CS - 1), bh = bhs >> 12, h = bh & 15, b = bh >> 4;
    float lr[4];
    #pragma unroll
    for (int r = 0; r < CR; r++) lr[r] = l_all[(size_t)r * CBHS + bhs];
    float m = fmaxf(fmaxf(lr[0], lr[1]), fmaxf(lr[2], lr[3]));
    float w[4], sum = 0.f;
    #pragma unroll
    for (int r = 0; r < CR; r++) { w[r] = expf(lr[r] - m); sum += w[r]; }
    float acc = 0.f;
    #pragma unroll
    for (int r = 0; r < CR; r++)
        acc += w[r] * bf2f(o_all[((size_t)r * CBHS + bhs) * CDH + d]);
    acc /= sum;
    attnout16[((size_t)(b * CS + s2)) * CD + h * 64 + d] = f2bf(acc);
}

extern "C" void kernel_launch(void* const* d_in, const int* in_sizes, int n_in,
                              void* d_out, int out_size, void* d_ws, size_t ws_size,
                              hipStream_t stream) {
    const float* x1   = (const float*)d_in[0];
    const float* x2   = (const float*)d_in[1];
    const float* Wqk  = (const float*)d_in[2];
    const float* Wv   = (const float*)d_in[3];
    const float* Wo   = (const float*)d_in[4];
    const float* ln1g = (const float*)d_in[5];
    const float* ln1b = (const float*)d_in[6];
    const float* W1   = (const float*)d_in[7];
    const float* bf1  = (const float*)d_in[8];
    const float* W2   = (const float*)d_in[9];
    const float* bf2  = (const float*)d_in[10];
    const float* ln2g = (const float*)d_in[11];
    const float* ln2b = (const float*)d_in[12];
    const float* rot  = (const float*)d_in[13];   // [64][128] row-major

    float* bufA = (float*)d_ws;                               // ln1 fp32 (bucket path)
    unsigned short* bufA16 = (unsigned short*)(bufA + (size_t)CBS * CD); // bf16 activations
    float* bufB = (float*)(bufA16 + (size_t)CBS * CD);        // qk fp32
    float* bufC = bufB + (size_t)CBS * CD;                    // v fp32
    unsigned short* o_all = (unsigned short*)(bufC + (size_t)CBS * CD);  // bf16
    float* l_all  = (float*)(o_all + (size_t)CR * CBHS * CDH);
    int* buckets  = (int*)(l_all + (size_t)CR * CBHS);
    int* sorted   = buckets + (size_t)CR * CBHS;
    unsigned short* WvT = (unsigned short*)(sorted + (size_t)CR * CBHS);
    unsigned short* WoT = WvT + (size_t)CD * CD;
    unsigned short* W1T = WoT + (size_t)CD * CD;              // [DFF][D]
    unsigned short* W2T = W1T + (size_t)CD * CDFF;            // [D][DFF]
    unsigned short* ffh16 = (unsigned short*)bufB;            // aliases qk+v (67 MB)
    unsigned short* attnout16 = bufA16;                       // reuse (ln1_16 dead)
    unsigned short* lnY16 = bufA16;                           // reuse again
    float* y1 = (float*)d_out;
    float* y2 = y1 + (size_t)CBS * CD;

    // 0. weight transposes (fp32 -> bf16, [K][N] -> [N][K])
    wtrans_kernel<<<dim3(CD / 64, CD / 64), 256, 0, stream>>>(Wv, WvT, CD, CD);
    wtrans_kernel<<<dim3(CD / 64, CD / 64), 256, 0, stream>>>(Wo, WoT, CD, CD);
    wtrans_kernel<<<dim3(CDFF / 64, CD / 64), 256, 0, stream>>>(W1, W1T, CD, CDFF);
    wtrans_kernel<<<dim3(CD / 64, CDFF / 64), 256, 0, stream>>>(W2, W2T, CDFF, CD);
    // 1. ln(x2) -> fp32 (bucket path) + bf16 (Wv MFMA path)
    ln_kernel<<<CBS, 256, 0, stream>>>(x2, ln1g, ln1b, bufA, bufA16);
    // 2. qk projection (fp32 — feeds bucketing, must stay fp32)
    gemm_f32<0><<<dim3(CD / 128, CBS / 128), 256, 0, stream>>>(bufA, Wqk, bufB, CBS, CD, CD);
    // 3. v projection (bf16 MFMA, fp32 out)
    gemm_bf16<0><<<dim3(CD / 128, CBS / 128), 256, 0, stream>>>(bufA16, WvT, nullptr, nullptr, bufC, CBS, CD, CD);
    // 4. LSH rotation GEMM + fused argmax -> buckets
    gemm_f32<4><<<dim3(1, CBHS / 128), 256, 0, stream>>>(bufB, rot, (float*)buckets, CBHS, 128, 64);
    // 5. stable counting sort per (r,b,h)
    sort_kernel<<<CR * CB * CH, 64, 0, stream>>>(buckets, sorted);
    // 6. chunked masked attention
    attn_kernel<<<dim3(CNCH, CR, CB * CH), 256, 0, stream>>>(bufB, bufC, buckets, sorted, o_all, l_all);
    // 7. round-weighted combine -> attnout bf16 (bufA16 reusable)
    combine_kernel<<<(CBHS * CDH) / 256, 256, 0, stream>>>(o_all, l_all, attnout16);
    // 8. y1 = attnout @ Wo + x1 (bf16 MFMA, residual epilogue)
    gemm_bf16<3><<<dim3(CD / 128, CBS / 128), 256, 0, stream>>>(attnout16, WoT, nullptr, x1, y1, CBS, CD, CD);
    // 9. ln(y1) -> bf16 only
    ln_kernel<<<CBS, 256, 0, stream>>>(y1, ln2g, ln2b, nullptr, lnY16);
    // 10. ffh = relu(ln_y1 @ W1 + bf1) -> bf16
    gemm_bf16<1><<<dim3(CDFF / 128, CBS / 128), 256, 0, stream>>>(lnY16, W1T, bf1, nullptr, ffh16, CBS, CDFF, CD);
    // 11. y2 = ffh @ W2 + bf2 + x2 (fp32 out)
    gemm_bf16<2><<<dim3(CD / 128, CBS / 128), 256, 0, stream>>>(ffh16, W2T, bf2, x2, y2, CBS, CD, CDFF);
}

// Round 3
// 861.882 us; speedup vs baseline: 3.1574x; 1.1993x over previous
//
#include <hip/hip_runtime.h>
#include <hip/hip_bf16.h>
#include <math.h>

// Problem constants
constexpr int CB   = 2;      // batch
constexpr int CS   = 4096;   // seq
constexpr int CD   = 1024;   // d_model
constexpr int CH   = 16;     // heads
constexpr int CDH  = 64;     // head dim
constexpr int CR   = 4;      // hash rounds
constexpr int CC   = 64;     // chunk length
constexpr int CNCH = 64;     // num chunks
constexpr int CDFF = 4096;
constexpr int CBS  = CB * CS;        // 8192 rows
constexpr int CBHS = CB * CH * CS;   // 131072

typedef __attribute__((ext_vector_type(8))) short short8;
typedef __attribute__((ext_vector_type(4))) short short4v;
typedef __attribute__((ext_vector_type(4))) float f32x4;

__device__ inline unsigned short f2bf(float f) {
    union { float f; unsigned int u; } a; a.f = f;
    unsigned int u = a.u;
    unsigned int r = (u + 0x7fffu + ((u >> 16) & 1u)) >> 16;
    return (unsigned short)r;
}
__device__ inline float bf2f(unsigned short h) {
    union { float f; unsigned int u; } a; a.u = ((unsigned int)h) << 16; return a.f;
}

#define AS3 __attribute__((address_space(3)))
#define AS1 __attribute__((address_space(1)))
__device__ inline void gload16(const unsigned short* g, unsigned short* l) {
    __builtin_amdgcn_global_load_lds((const AS1 unsigned int*)g,
                                     (AS3 unsigned int*)l, 16, 0, 0);
}

// 8-short load from 8B-aligned (not necessarily 16B-aligned) LDS address
__device__ inline short8 ld_short8_u(const unsigned short* p) {
    short4v a = *(const short4v*)p;
    short4v b = *(const short4v*)(p + 4);
    short8 r;
    r[0] = a[0]; r[1] = a[1]; r[2] = a[2]; r[3] = a[3];
    r[4] = b[0]; r[5] = b[1]; r[6] = b[2]; r[7] = b[3];
    return r;
}
__device__ inline short8 pack8(float4 a, float4 b) {
    short8 r;
    r[0] = (short)f2bf(a.x); r[1] = (short)f2bf(a.y);
    r[2] = (short)f2bf(a.z); r[3] = (short)f2bf(a.w);
    r[4] = (short)f2bf(b.x); r[5] = (short)f2bf(b.y);
    r[6] = (short)f2bf(b.z); r[7] = (short)f2bf(b.w);
    return r;
}

// ---------------- LayerNorm: one block per row of D=1024; fp32 + bf16 out ----
__global__ __launch_bounds__(256) void ln_kernel(const float* __restrict__ x,
        const float* __restrict__ g, const float* __restrict__ bta,
        float* __restrict__ out, unsigned short* __restrict__ out16) {
    int row = blockIdx.x;
    int t = threadIdx.x;
    const float* xr = x + (size_t)row * CD;
    float4 v = *(const float4*)(xr + t * 4);
    float s  = v.x + v.y + v.z + v.w;
    float ss = v.x * v.x + v.y * v.y + v.z * v.z + v.w * v.w;
    #pragma unroll
    for (int off = 1; off < 64; off <<= 1) {
        s  += __shfl_xor(s, off);
        ss += __shfl_xor(ss, off);
    }
    __shared__ float ws_[4], wss_[4];
    int wid = t >> 6;
    if ((t & 63) == 0) { ws_[wid] = s; wss_[wid] = ss; }
    __syncthreads();
    s  = ws_[0] + ws_[1] + ws_[2] + ws_[3];
    ss = wss_[0] + wss_[1] + wss_[2] + wss_[3];
    float mean = s * (1.0f / CD);
    float var  = ss * (1.0f / CD) - mean * mean;
    float rstd = rsqrtf(var + 1e-5f);
    float4 gv = *(const float4*)(g + t * 4);
    float4 bv = *(const float4*)(bta + t * 4);
    float4 o;
    o.x = (v.x - mean) * rstd * gv.x + bv.x;
    o.y = (v.y - mean) * rstd * gv.y + bv.y;
    o.z = (v.z - mean) * rstd * gv.z + bv.z;
    o.w = (v.w - mean) * rstd * gv.w + bv.w;
    if (out) *(float4*)(out + (size_t)row * CD + t * 4) = o;
    if (out16) {
        ushort4 h; h.x = f2bf(o.x); h.y = f2bf(o.y); h.z = f2bf(o.z); h.w = f2bf(o.w);
        *(ushort4*)(out16 + (size_t)row * CD + t * 4) = h;
    }
}

// ---------------- weight transpose + fp32->bf16: W[K][N] -> WT[N][K] --------
__global__ __launch_bounds__(256) void wtrans_kernel(const float* __restrict__ W,
        unsigned short* __restrict__ WT, int K, int N) {
    __shared__ float tile[64][65];
    int n0 = blockIdx.x * 64, k0 = blockIdx.y * 64;
    int tid = threadIdx.x;
    int r = tid >> 4, c4 = tid & 15;
    #pragma unroll
    for (int it = 0; it < 4; ++it) {
        int row = r + it * 16;
        float4 v = *(const float4*)(W + (size_t)(k0 + row) * N + n0 + c4 * 4);
        tile[row][c4 * 4 + 0] = v.x; tile[row][c4 * 4 + 1] = v.y;
        tile[row][c4 * 4 + 2] = v.z; tile[row][c4 * 4 + 3] = v.w;
    }
    __syncthreads();
    #pragma unroll
    for (int it = 0; it < 4; ++it) {
        int nrow = r + it * 16;
        ushort4 h;
        h.x = f2bf(tile[c4 * 4 + 0][nrow]);
        h.y = f2bf(tile[c4 * 4 + 1][nrow]);
        h.z = f2bf(tile[c4 * 4 + 2][nrow]);
        h.w = f2bf(tile[c4 * 4 + 3][nrow]);
        *(ushort4*)(WT + (size_t)(n0 + nrow) * K + k0 + c4 * 4) = h;
    }
}

// ---------------- bf16 MFMA GEMM: C[M][N] = A[M][K] @ BT[N][K]^T ------------
template<int EPI>
__global__ __launch_bounds__(256) void gemm_bf16(const unsigned short* __restrict__ A,
        const unsigned short* __restrict__ BT, const float* __restrict__ bias,
        const float* __restrict__ res, void* __restrict__ outp,
        int M, int N, int K) {
    __shared__ __align__(16) unsigned short As[128 * 32];
    __shared__ __align__(16) unsigned short Bs[128 * 32];
    int tid = threadIdx.x;
    int w = tid >> 6, l = tid & 63;
    int m0 = blockIdx.y * 128, n0 = blockIdx.x * 128;
    int wm = (w >> 1) * 64, wn = (w & 1) * 64;

    const unsigned short* gA[2]; const unsigned short* gB[2];
    unsigned short* ldsA[2]; unsigned short* ldsB[2];
    int gchunk = (l & 3) ^ ((l >> 3) & 3);
    #pragma unroll
    for (int s = 0; s < 2; ++s) {
        int j = w * 2 + s;
        int R = j * 16 + (l >> 2);
        gA[s] = A + (size_t)(m0 + R) * K + gchunk * 8;
        gB[s] = BT + (size_t)(n0 + R) * K + gchunk * 8;
        ldsA[s] = As + j * 512;
        ldsB[s] = Bs + j * 512;
    }
    int p = (l >> 4) ^ (((l & 15) >> 1) & 3);
    int aoff = (wm + (l & 15)) * 32 + p * 8;
    int boff = (wn + (l & 15)) * 32 + p * 8;

    f32x4 acc[4][4];
    #pragma unroll
    for (int i = 0; i < 4; i++)
        #pragma unroll
        for (int j = 0; j < 4; j++) acc[i][j] = (f32x4)(0.f);

    for (int k0 = 0; k0 < K; k0 += 32) {
        gload16(gA[0] + k0, ldsA[0]);
        gload16(gA[1] + k0, ldsA[1]);
        gload16(gB[0] + k0, ldsB[0]);
        gload16(gB[1] + k0, ldsB[1]);
        __syncthreads();
        short8 af[4], bf[4];
        #pragma unroll
        for (int im = 0; im < 4; ++im) af[im] = *(const short8*)(As + aoff + im * 512);
        #pragma unroll
        for (int in = 0; in < 4; ++in) bf[in] = *(const short8*)(Bs + boff + in * 512);
        #pragma unroll
        for (int im = 0; im < 4; ++im)
            #pragma unroll
            for (int in = 0; in < 4; ++in)
                acc[im][in] = __builtin_amdgcn_mfma_f32_16x16x32_bf16(
                    af[im], bf[in], acc[im][in], 0, 0, 0);
        __syncthreads();
    }

    float bv[4];
    if (EPI == 1 || EPI == 2) {
        #pragma unroll
        for (int in = 0; in < 4; ++in) bv[in] = bias[n0 + wn + in * 16 + (l & 15)];
    }
    #pragma unroll
    for (int im = 0; im < 4; ++im) {
        #pragma unroll
        for (int in = 0; in < 4; ++in) {
            int n = n0 + wn + in * 16 + (l & 15);
            #pragma unroll
            for (int r = 0; r < 4; ++r) {
                int m = m0 + wm + im * 16 + (l >> 4) * 4 + r;
                float v = acc[im][in][r];
                if (EPI == 1) {
                    v = fmaxf(v + bv[in], 0.f);
                    ((unsigned short*)outp)[(size_t)m * N + n] = f2bf(v);
                } else {
                    if (EPI == 2) v += bv[in] + res[(size_t)m * N + n];
                    if (EPI == 3) v += res[(size_t)m * N + n];
                    ((float*)outp)[(size_t)m * N + n] = v;
                }
            }
        }
    }
}

// ---------------- fp32 tiled GEMM (bucket path only) ----------------
template<int EPI>
__global__ __launch_bounds__(256) void gemm_f32(const float* __restrict__ A,
        const float* __restrict__ W, float* __restrict__ out,
        int M, int N, int K) {
    __shared__ __align__(16) float As[16][132];
    __shared__ __align__(16) float Bs[16][132];
    int tid = threadIdx.x;
    int n0 = blockIdx.x * 128;
    int m0 = blockIdx.y * 128;
    int ty = tid >> 4, tx = tid & 15;
    float acc[8][8];
    #pragma unroll
    for (int i = 0; i < 8; i++)
        #pragma unroll
        for (int j = 0; j < 8; j++) acc[i][j] = 0.f;

    for (int k0 = 0; k0 < K; k0 += 16) {
        #pragma unroll
        for (int it = 0; it < 2; ++it) {
            int f4 = tid + it * 256;
            int row = f4 >> 2, c4 = f4 & 3;
            float4 av = *(const float4*)(A + (size_t)(m0 + row) * K + k0 + c4 * 4);
            As[c4 * 4 + 0][row] = av.x;
            As[c4 * 4 + 1][row] = av.y;
            As[c4 * 4 + 2][row] = av.z;
            As[c4 * 4 + 3][row] = av.w;
        }
        #pragma unroll
        for (int it = 0; it < 2; ++it) {
            int f4 = tid + it * 256;
            int kr = f4 >> 5, c4 = f4 & 31;
            *(float4*)(&Bs[kr][c4 * 4]) =
                *(const float4*)(W + (size_t)(k0 + kr) * N + n0 + c4 * 4);
        }
        __syncthreads();
        #pragma unroll
        for (int kk = 0; kk < 16; ++kk) {
            float4 a0 = *(const float4*)(&As[kk][ty * 8]);
            float4 a1 = *(const float4*)(&As[kk][ty * 8 + 4]);
            float4 b0 = *(const float4*)(&Bs[kk][tx * 8]);
            float4 b1 = *(const float4*)(&Bs[kk][tx * 8 + 4]);
            float am[8] = {a0.x, a0.y, a0.z, a0.w, a1.x, a1.y, a1.z, a1.w};
            float bn[8] = {b0.x, b0.y, b0.z, b0.w, b1.x, b1.y, b1.z, b1.w};
            #pragma unroll
            for (int i = 0; i < 8; i++)
                #pragma unroll
                for (int j = 0; j < 8; j++)
                    acc[i][j] = fmaf(am[i], bn[j], acc[i][j]);
        }
        __syncthreads();
    }

    if (EPI == 4) {
        int* ibuck = (int*)out;
        int q = tx & 3, r = tx >> 2;      // col = r*32 + q*8 + j
        #pragma unroll
        for (int i = 0; i < 8; i++) {
            int m = m0 + ty * 8 + i;
            float bestP = -3.4e38f, bestN = -3.4e38f;
            int biP = 0, biN = 0;
            #pragma unroll
            for (int j = 0; j < 8; j++) {
                float v = acc[i][j];
                if ( v > bestP) { bestP =  v; biP = q * 8 + j; }
                if (-v > bestN) { bestN = -v; biN = q * 8 + j; }
            }
            #pragma unroll
            for (int off = 1; off < 4; off <<= 1) {
                float oP = __shfl_xor(bestP, off); int oiP = __shfl_xor(biP, off);
                float oN = __shfl_xor(bestN, off); int oiN = __shfl_xor(biN, off);
                if (oP > bestP || (oP == bestP && oiP < biP)) { bestP = oP; biP = oiP; }
                if (oN > bestN || (oN == bestN && oiN < biN)) { bestN = oN; biN = oiN; }
            }
            if (q == 0) {
                int bi = (bestP >= bestN) ? biP : (biN + 32);
                int hh = m & 15, ss2 = (m >> 4) & (CS - 1), bb2 = m >> 16;
                ibuck[((size_t)((r * CB + bb2) * CH + hh)) * CS + ss2] = bi;
            }
        }
        return;
    }

    #pragma unroll
    for (int i = 0; i < 8; i++) {
        int m = m0 + ty * 8 + i;
        #pragma unroll
        for (int j4 = 0; j4 < 2; j4++) {
            int n = n0 + tx * 8 + j4 * 4;
            float4 v;
            v.x = acc[i][j4 * 4 + 0]; v.y = acc[i][j4 * 4 + 1];
            v.z = acc[i][j4 * 4 + 2]; v.w = acc[i][j4 * 4 + 3];
            *(float4*)(out + (size_t)m * N + n) = v;
        }
    }
}

// ---------------- stable counting sort per (r,b,h): one wave ----------------
__global__ __launch_bounds__(64) void sort_kernel(const int* __restrict__ buckets,
                                                  int* __restrict__ sorted_pos) {
    int g = blockIdx.x;                  // rbh
    const int* bk = buckets + (size_t)g * CS;
    __shared__ int hist[64][65];
    __shared__ int bstart[64];
    int t = threadIdx.x;
    #pragma unroll
    for (int i = 0; i < 64; i++) hist[t][i] = 0;
    __syncthreads();
    int base = t * 64;
    for (int i = 0; i < 64; i++) { int b = bk[base + i]; hist[t][b]++; }
    __syncthreads();
    int run = 0;
    for (int tt = 0; tt < 64; tt++) {
        int c = hist[tt][t];
        hist[tt][t] = run;
        run += c;
    }
    int x = run;
    #pragma unroll
    for (int off = 1; off < 64; off <<= 1) {
        int y = __shfl_up(x, off);
        if (t >= off) x += y;
    }
    bstart[t] = x - run;
    __syncthreads();
    for (int i = 0; i < 64; i++) {
        int b = bk[base + i];
        int rank = bstart[b] + hist[t][b];
        hist[t][b]++;
        sorted_pos[(size_t)g * CS + rank] = base + i;
    }
}

// ---------------- chunked LSH attention (bf16 MFMA) -------------------------
// One block per (r,b,h,chunk); 4 waves; wave w owns q-rows [16w,16w+16).
// QK^T: 16x16x32 MFMA, Q raw bf16 from global, K-hat bf16 from LDS.
// Softmax in C-layout regs (in-wave). P -> LDS[64][132] -> PV MFMA with
// V^T staged in LDS[64][132] bf16.
__global__ __launch_bounds__(256) void attn_kernel(const float* __restrict__ qkbuf,
        const float* __restrict__ vbuf, const int* __restrict__ buckets,
        const int* __restrict__ sorted, unsigned short* __restrict__ o_all,
        float* __restrict__ l_all) {
    int n  = blockIdx.x;
    int r  = blockIdx.y;
    int bh = blockIdx.z;
    int b = bh >> 4, h = bh & 15;
    int rbh = (r * CB + b) * CH + h;
    int tid = threadIdx.x;
    int w = tid >> 6, l = tid & 63;
    int l4 = l & 15, qd = l >> 4;

    __shared__ int pk[128];
    __shared__ int bkk[128];
    __shared__ __align__(16) unsigned short Ks[128 * 72];   // K-hat [kk][d]
    __shared__ __align__(16) unsigned short Ps[64 * 132];   // P [m][kk]
    __shared__ __align__(16) unsigned short VsT[64 * 132];  // V^T [d][kk]

    int prev = (n + CNCH - 1) & (CNCH - 1);
    if (tid < 128) {
        int i = tid & 63;
        int ch = (tid < 64) ? n : prev;
        int p = sorted[(size_t)rbh * CS + ch * CC + i];
        pk[tid] = p;
        bkk[tid] = buckets[(size_t)rbh * CS + p];
    }
    __syncthreads();

    const float* qbase = qkbuf + (size_t)b * CS * CD + h * 64;
    const float* vbase = vbuf  + (size_t)b * CS * CD + h * 64;

    // K staging: load row, 16-lane shfl reduce for L2 norm, write bf16
    #pragma unroll
    for (int it = 0; it < 8; ++it) {
        int f4 = tid + it * 256;            // 0..2047
        int kk = f4 >> 4, d4 = f4 & 15;
        float4 v = *(const float4*)(qbase + (size_t)pk[kk] * CD + d4 * 4);
        float ss = v.x * v.x + v.y * v.y + v.z * v.z + v.w * v.w;
        ss += __shfl_xor(ss, 1); ss += __shfl_xor(ss, 2);
        ss += __shfl_xor(ss, 4); ss += __shfl_xor(ss, 8);
        float rn = 1.f / (sqrtf(ss) + 1e-6f);
        ushort4 hv;
        hv.x = f2bf(v.x * rn); hv.y = f2bf(v.y * rn);
        hv.z = f2bf(v.z * rn); hv.w = f2bf(v.w * rn);
        *(ushort4*)&Ks[kk * 72 + d4 * 4] = hv;
    }
    // V staging transposed: lane d=l, two kk rows per iter, packed b32 write
    #pragma unroll
    for (int it = 0; it < 16; ++it) {
        int kkp = w * 16 + it;              // 0..63 (pair index)
        int r0 = pk[2 * kkp], r1 = pk[2 * kkp + 1];
        float v0 = vbase[(size_t)r0 * CD + l];
        float v1 = vbase[(size_t)r1 * CD + l];
        unsigned int pck = (unsigned int)f2bf(v0) | ((unsigned int)f2bf(v1) << 16);
        *(unsigned int*)&VsT[l * 132 + 2 * kkp] = pck;
    }
    // Q A-fragments straight from global (rows L2-hot), raw bf16
    int mstrip = w * 16;
    const float* qptr = qbase + (size_t)pk[mstrip + l4] * CD + qd * 8;
    float4 qa0 = *(const float4*)(qptr);
    float4 qa1 = *(const float4*)(qptr + 4);
    float4 qb0 = *(const float4*)(qptr + 32);
    float4 qb1 = *(const float4*)(qptr + 36);
    short8 afA = pack8(qa0, qa1);
    short8 afB = pack8(qb0, qb1);
    __syncthreads();

    // QK^T: 8 n-tiles (128 keys), 2 k-steps
    f32x4 sa[8];
    #pragma unroll
    for (int t = 0; t < 8; ++t) sa[t] = (f32x4)(0.f);
    #pragma unroll
    for (int t = 0; t < 8; ++t) {
        const unsigned short* kb = &Ks[(t * 16 + l4) * 72 + qd * 8];
        short8 b0 = *(const short8*)(kb);
        short8 b1 = *(const short8*)(kb + 32);
        sa[t] = __builtin_amdgcn_mfma_f32_16x16x32_bf16(afA, b0, sa[t], 0, 0, 0);
        sa[t] = __builtin_amdgcn_mfma_f32_16x16x32_bf16(afB, b1, sa[t], 0, 0, 0);
    }

    // masks + softmax; C-layout: col = t*16+l4 (key), row = mstrip+4*qd+rr (query)
    int rowb[4], rowp[4];
    #pragma unroll
    for (int rr = 0; rr < 4; ++rr) {
        int m = mstrip + 4 * qd + rr;
        rowb[rr] = bkk[m]; rowp[rr] = pk[m];
    }
    float mx[4] = {-3.4e38f, -3.4e38f, -3.4e38f, -3.4e38f};
    #pragma unroll
    for (int t = 0; t < 8; ++t) {
        int cb = bkk[t * 16 + l4], cp = pk[t * 16 + l4];
        #pragma unroll
        for (int rr = 0; rr < 4; ++rr) {
            float v = sa[t][rr] * 0.125f;
            if (rowb[rr] != cb) v = -1e9f;
            if (rowp[rr] == cp) v = -1e5f;
            sa[t][rr] = v;
            mx[rr] = fmaxf(mx[rr], v);
        }
    }
    #pragma unroll
    for (int rr = 0; rr < 4; ++rr) {
        mx[rr] = fmaxf(mx[rr], __shfl_xor(mx[rr], 1));
        mx[rr] = fmaxf(mx[rr], __shfl_xor(mx[rr], 2));
        mx[rr] = fmaxf(mx[rr], __shfl_xor(mx[rr], 4));
        mx[rr] = fmaxf(mx[rr], __shfl_xor(mx[rr], 8));
    }
    float sum[4] = {0.f, 0.f, 0.f, 0.f};
    #pragma unroll
    for (int t = 0; t < 8; ++t)
        #pragma unroll
        for (int rr = 0; rr < 4; ++rr) {
            float e = expf(sa[t][rr] - mx[rr]);
            sa[t][rr] = e;
            sum[rr] += e;
        }
    #pragma unroll
    for (int rr = 0; rr < 4; ++rr) {
        sum[rr] += __shfl_xor(sum[rr], 1);
        sum[rr] += __shfl_xor(sum[rr], 2);
        sum[rr] += __shfl_xor(sum[rr], 4);
        sum[rr] += __shfl_xor(sum[rr], 8);
    }
    if (l4 == 0) {
        #pragma unroll
        for (int rr = 0; rr < 4; ++rr)
            l_all[(size_t)rbh * CS + rowp[rr]] = mx[rr] + logf(sum[rr]);
    }

    // P -> LDS (rows are wave-private; no barrier needed)
    float rs[4];
    #pragma unroll
    for (int rr = 0; rr < 4; ++rr) rs[rr] = 1.f / sum[rr];
    #pragma unroll
    for (int t = 0; t < 8; ++t)
        #pragma unroll
        for (int rr = 0; rr < 4; ++rr)
            Ps[(mstrip + 4 * qd + rr) * 132 + t * 16 + l4] = f2bf(sa[t][rr] * rs[rr]);

    // PV: O[m][d], 4 n-tiles (d), 4 k-steps (kk)
    f32x4 oa[4];
    #pragma unroll
    for (int nt = 0; nt < 4; ++nt) oa[nt] = (f32x4)(0.f);
    #pragma unroll
    for (int ks = 0; ks < 4; ++ks) {
        short8 ap = ld_short8_u(&Ps[(mstrip + l4) * 132 + ks * 32 + qd * 8]);
        #pragma unroll
        for (int nt = 0; nt < 4; ++nt) {
            short8 bv = ld_short8_u(&VsT[(nt * 16 + l4) * 132 + ks * 32 + qd * 8]);
            oa[nt] = __builtin_amdgcn_mfma_f32_16x16x32_bf16(ap, bv, oa[nt], 0, 0, 0);
        }
    }
    // scatter O (bf16) back to original positions
    #pragma unroll
    for (int nt = 0; nt < 4; ++nt)
        #pragma unroll
        for (int rr = 0; rr < 4; ++rr)
            o_all[((size_t)rbh * CS + rowp[rr]) * CDH + nt * 16 + l4] = f2bf(oa[nt][rr]);
}

// ---------------- combine rounds: softmax over R of logsumexp; bf16 out -----
__global__ __launch_bounds__(256) void combine_kernel(const unsigned short* __restrict__ o_all,
        const float* __restrict__ l_all, unsigned short* __restrict__ attnout16) {
    int idx = blockIdx.x * 256 + threadIdx.x;
    int d = idx & 63, bhs = idx >> 6;
    int s2 = bhs & (CS - 1), bh = bhs >> 12, h = bh & 15, b = bh >> 4;
    float lr[4];
    #pragma unroll
    for (int r = 0; r < CR; r++) lr[r] = l_all[(size_t)r * CBHS + bhs];
    float m = fmaxf(fmaxf(lr[0], lr[1]), fmaxf(lr[2], lr[3]));
    float w[4], sum = 0.f;
    #pragma unroll
    for (int r = 0; r < CR; r++) { w[r] = expf(lr[r] - m); sum += w[r]; }
    float acc = 0.f;
    #pragma unroll
    for (int r = 0; r < CR; r++)
        acc += w[r] * bf2f(o_all[((size_t)r * CBHS + bhs) * CDH + d]);
    acc /= sum;
    attnout16[((size_t)(b * CS + s2)) * CD + h * 64 + d] = f2bf(acc);
}

extern "C" void kernel_launch(void* const* d_in, const int* in_sizes, int n_in,
                              void* d_out, int out_size, void* d_ws, size_t ws_size,
                              hipStream_t stream) {
    const float* x1   = (const float*)d_in[0];
    const float* x2   = (const float*)d_in[1];
    const float* Wqk  = (const float*)d_in[2];
    const float* Wv   = (const float*)d_in[3];
    const float* Wo   = (const float*)d_in[4];
    const float* ln1g = (const float*)d_in[5];
    const float* ln1b = (const float*)d_in[6];
    const float* W1   = (const float*)d_in[7];
    const float* bf1  = (const float*)d_in[8];
    const float* W2   = (const float*)d_in[9];
    const float* bf2  = (const float*)d_in[10];
    const float* ln2g = (const float*)d_in[11];
    const float* ln2b = (const float*)d_in[12];
    const float* rot  = (const float*)d_in[13];   // [64][128] row-major

    float* bufA = (float*)d_ws;                               // ln1 fp32 (bucket path)
    unsigned short* bufA16 = (unsigned short*)(bufA + (size_t)CBS * CD); // bf16 activations
    float* bufB = (float*)(bufA16 + (size_t)CBS * CD);        // qk fp32
    float* bufC = bufB + (size_t)CBS * CD;                    // v fp32
    unsigned short* o_all = (unsigned short*)(bufC + (size_t)CBS * CD);  // bf16
    float* l_all  = (float*)(o_all + (size_t)CR * CBHS * CDH);
    int* buckets  = (int*)(l_all + (size_t)CR * CBHS);
    int* sorted   = buckets + (size_t)CR * CBHS;
    unsigned short* WvT = (unsigned short*)(sorted + (size_t)CR * CBHS);
    unsigned short* WoT = WvT + (size_t)CD * CD;
    unsigned short* W1T = WoT + (size_t)CD * CD;              // [DFF][D]
    unsigned short* W2T = W1T + (size_t)CD * CDFF;            // [D][DFF]
    unsigned short* ffh16 = (unsigned short*)bufB;            // aliases qk+v
    unsigned short* attnout16 = bufA16;                       // reuse (ln1_16 dead)
    unsigned short* lnY16 = bufA16;                           // reuse again
    float* y1 = (float*)d_out;
    float* y2 = y1 + (size_t)CBS * CD;

    // 0. weight transposes (fp32 -> bf16, [K][N] -> [N][K])
    wtrans_kernel<<<dim3(CD / 64, CD / 64), 256, 0, stream>>>(Wv, WvT, CD, CD);
    wtrans_kernel<<<dim3(CD / 64, CD / 64), 256, 0, stream>>>(Wo, WoT, CD, CD);
    wtrans_kernel<<<dim3(CDFF / 64, CD / 64), 256, 0, stream>>>(W1, W1T, CD, CDFF);
    wtrans_kernel<<<dim3(CD / 64, CDFF / 64), 256, 0, stream>>>(W2, W2T, CDFF, CD);
    // 1. ln(x2) -> fp32 (bucket path) + bf16 (Wv MFMA path)
    ln_kernel<<<CBS, 256, 0, stream>>>(x2, ln1g, ln1b, bufA, bufA16);
    // 2. qk projection (fp32 — feeds bucketing, must stay fp32)
    gemm_f32<0><<<dim3(CD / 128, CBS / 128), 256, 0, stream>>>(bufA, Wqk, bufB, CBS, CD, CD);
    // 3. v projection (bf16 MFMA, fp32 out)
    gemm_bf16<0><<<dim3(CD / 128, CBS / 128), 256, 0, stream>>>(bufA16, WvT, nullptr, nullptr, bufC, CBS, CD, CD);
    // 4. LSH rotation GEMM + fused argmax -> buckets
    gemm_f32<4><<<dim3(1, CBHS / 128), 256, 0, stream>>>(bufB, rot, (float*)buckets, CBHS, 128, 64);
    // 5. stable counting sort per (r,b,h)
    sort_kernel<<<CR * CB * CH, 64, 0, stream>>>(buckets, sorted);
    // 6. chunked masked attention (bf16 MFMA)
    attn_kernel<<<dim3(CNCH, CR, CB * CH), 256, 0, stream>>>(bufB, bufC, buckets, sorted, o_all, l_all);
    // 7. round-weighted combine -> attnout bf16
    combine_kernel<<<(CBHS * CDH) / 256, 256, 0, stream>>>(o_all, l_all, attnout16);
    // 8. y1 = attnout @ Wo + x1 (bf16 MFMA, residual epilogue)
    gemm_bf16<3><<<dim3(CD / 128, CBS / 128), 256, 0, stream>>>(attnout16, WoT, nullptr, x1, y1, CBS, CD, CD);
    // 9. ln(y1) -> bf16 only
    ln_kernel<<<CBS, 256, 0, stream>>>(y1, ln2g, ln2b, nullptr, lnY16);
    // 10. ffh = relu(ln_y1 @ W1 + bf1) -> bf16
    gemm_bf16<1><<<dim3(CDFF / 128, CBS / 128), 256, 0, stream>>>(lnY16, W1T, bf1, nullptr, ffh16, CBS, CDFF, CD);
    // 11. y2 = ffh @ W2 + bf2 + x2 (fp32 out)
    gemm_bf16<2><<<dim3(CD / 128, CBS / 128), 256, 0, stream>>>(ffh16, W2T, bf2, x2, y2, CBS, CD, CDFF);
}

// Round 4
// 703.930 us; speedup vs baseline: 3.8659x; 1.2244x over previous
//
#include <hip/hip_runtime.h>
#include <hip/hip_bf16.h>
#include <math.h>

// Problem constants
constexpr int CB   = 2;      // batch
constexpr int CS   = 4096;   // seq
constexpr int CD   = 1024;   // d_model
constexpr int CH   = 16;     // heads
constexpr int CDH  = 64;     // head dim
constexpr int CR   = 4;      // hash rounds
constexpr int CC   = 64;     // chunk length
constexpr int CNCH = 64;     // num chunks
constexpr int CDFF = 4096;
constexpr int CBS  = CB * CS;        // 8192 rows
constexpr int CBHS = CB * CH * CS;   // 131072

typedef __attribute__((ext_vector_type(8))) short short8;
typedef __attribute__((ext_vector_type(4))) short short4v;
typedef __attribute__((ext_vector_type(4))) float f32x4;

__device__ inline unsigned short f2bf(float f) {
    union { float f; unsigned int u; } a; a.f = f;
    unsigned int u = a.u;
    unsigned int r = (u + 0x7fffu + ((u >> 16) & 1u)) >> 16;
    return (unsigned short)r;
}
__device__ inline float bf2f(unsigned short h) {
    union { float f; unsigned int u; } a; a.u = ((unsigned int)h) << 16; return a.f;
}

#define AS3 __attribute__((address_space(3)))
#define AS1 __attribute__((address_space(1)))
__device__ inline void gload16(const unsigned short* g, unsigned short* l) {
    __builtin_amdgcn_global_load_lds((const AS1 unsigned int*)g,
                                     (AS3 unsigned int*)l, 16, 0, 0);
}

// 8-short load from 8B-aligned (not necessarily 16B-aligned) LDS address
__device__ inline short8 ld_short8_u(const unsigned short* p) {
    short4v a = *(const short4v*)p;
    short4v b = *(const short4v*)(p + 4);
    short8 r;
    r[0] = a[0]; r[1] = a[1]; r[2] = a[2]; r[3] = a[3];
    r[4] = b[0]; r[5] = b[1]; r[6] = b[2]; r[7] = b[3];
    return r;
}
__device__ inline short8 pack8(float4 a, float4 b) {
    short8 r;
    r[0] = (short)f2bf(a.x); r[1] = (short)f2bf(a.y);
    r[2] = (short)f2bf(a.z); r[3] = (short)f2bf(a.w);
    r[4] = (short)f2bf(b.x); r[5] = (short)f2bf(b.y);
    r[6] = (short)f2bf(b.z); r[7] = (short)f2bf(b.w);
    return r;
}

// ---------------- LayerNorm: one block per row; bf16 hi (+ optional lo) -----
__global__ __launch_bounds__(256) void ln_kernel(const float* __restrict__ x,
        const float* __restrict__ g, const float* __restrict__ bta,
        unsigned short* __restrict__ out16, unsigned short* __restrict__ out16lo) {
    int row = blockIdx.x;
    int t = threadIdx.x;
    const float* xr = x + (size_t)row * CD;
    float4 v = *(const float4*)(xr + t * 4);
    float s  = v.x + v.y + v.z + v.w;
    float ss = v.x * v.x + v.y * v.y + v.z * v.z + v.w * v.w;
    #pragma unroll
    for (int off = 1; off < 64; off <<= 1) {
        s  += __shfl_xor(s, off);
        ss += __shfl_xor(ss, off);
    }
    __shared__ float ws_[4], wss_[4];
    int wid = t >> 6;
    if ((t & 63) == 0) { ws_[wid] = s; wss_[wid] = ss; }
    __syncthreads();
    s  = ws_[0] + ws_[1] + ws_[2] + ws_[3];
    ss = wss_[0] + wss_[1] + wss_[2] + wss_[3];
    float mean = s * (1.0f / CD);
    float var  = ss * (1.0f / CD) - mean * mean;
    float rstd = rsqrtf(var + 1e-5f);
    float4 gv = *(const float4*)(g + t * 4);
    float4 bv = *(const float4*)(bta + t * 4);
    float4 o;
    o.x = (v.x - mean) * rstd * gv.x + bv.x;
    o.y = (v.y - mean) * rstd * gv.y + bv.y;
    o.z = (v.z - mean) * rstd * gv.z + bv.z;
    o.w = (v.w - mean) * rstd * gv.w + bv.w;
    ushort4 h; h.x = f2bf(o.x); h.y = f2bf(o.y); h.z = f2bf(o.z); h.w = f2bf(o.w);
    *(ushort4*)(out16 + (size_t)row * CD + t * 4) = h;
    if (out16lo) {
        ushort4 lo;
        lo.x = f2bf(o.x - bf2f(h.x)); lo.y = f2bf(o.y - bf2f(h.y));
        lo.z = f2bf(o.z - bf2f(h.z)); lo.w = f2bf(o.w - bf2f(h.w));
        *(ushort4*)(out16lo + (size_t)row * CD + t * 4) = lo;
    }
}

// ------- weight transpose + fp32->bf16 (hi + optional lo): W[K][N]->WT[N][K]
__global__ __launch_bounds__(256) void wtrans_kernel(const float* __restrict__ W,
        unsigned short* __restrict__ WT, unsigned short* __restrict__ WTlo,
        int K, int N) {
    __shared__ float tile[64][65];
    int n0 = blockIdx.x * 64, k0 = blockIdx.y * 64;
    int tid = threadIdx.x;
    int r = tid >> 4, c4 = tid & 15;
    #pragma unroll
    for (int it = 0; it < 4; ++it) {
        int row = r + it * 16;
        float4 v = *(const float4*)(W + (size_t)(k0 + row) * N + n0 + c4 * 4);
        tile[row][c4 * 4 + 0] = v.x; tile[row][c4 * 4 + 1] = v.y;
        tile[row][c4 * 4 + 2] = v.z; tile[row][c4 * 4 + 3] = v.w;
    }
    __syncthreads();
    #pragma unroll
    for (int it = 0; it < 4; ++it) {
        int nrow = r + it * 16;
        float f0 = tile[c4 * 4 + 0][nrow], f1 = tile[c4 * 4 + 1][nrow];
        float f2 = tile[c4 * 4 + 2][nrow], f3 = tile[c4 * 4 + 3][nrow];
        ushort4 h;
        h.x = f2bf(f0); h.y = f2bf(f1); h.z = f2bf(f2); h.w = f2bf(f3);
        *(ushort4*)(WT + (size_t)(n0 + nrow) * K + k0 + c4 * 4) = h;
        if (WTlo) {
            ushort4 lo;
            lo.x = f2bf(f0 - bf2f(h.x)); lo.y = f2bf(f1 - bf2f(h.y));
            lo.z = f2bf(f2 - bf2f(h.z)); lo.w = f2bf(f3 - bf2f(h.w));
            *(ushort4*)(WTlo + (size_t)(n0 + nrow) * K + k0 + c4 * 4) = lo;
        }
    }
}

// ---------------- bf16 MFMA GEMM: C[M][N] = A[M][K] @ BT[N][K]^T ------------
template<int EPI>
__global__ __launch_bounds__(256) void gemm_bf16(const unsigned short* __restrict__ A,
        const unsigned short* __restrict__ BT, const float* __restrict__ bias,
        const float* __restrict__ res, void* __restrict__ outp,
        int M, int N, int K) {
    __shared__ __align__(16) unsigned short As[128 * 32];
    __shared__ __align__(16) unsigned short Bs[128 * 32];
    int tid = threadIdx.x;
    int w = tid >> 6, l = tid & 63;
    int m0 = blockIdx.y * 128, n0 = blockIdx.x * 128;
    int wm = (w >> 1) * 64, wn = (w & 1) * 64;

    const unsigned short* gA[2]; const unsigned short* gB[2];
    unsigned short* ldsA[2]; unsigned short* ldsB[2];
    int gchunk = (l & 3) ^ ((l >> 3) & 3);
    #pragma unroll
    for (int s = 0; s < 2; ++s) {
        int j = w * 2 + s;
        int R = j * 16 + (l >> 2);
        gA[s] = A + (size_t)(m0 + R) * K + gchunk * 8;
        gB[s] = BT + (size_t)(n0 + R) * K + gchunk * 8;
        ldsA[s] = As + j * 512;
        ldsB[s] = Bs + j * 512;
    }
    int p = (l >> 4) ^ (((l & 15) >> 1) & 3);
    int aoff = (wm + (l & 15)) * 32 + p * 8;
    int boff = (wn + (l & 15)) * 32 + p * 8;

    f32x4 acc[4][4];
    #pragma unroll
    for (int i = 0; i < 4; i++)
        #pragma unroll
        for (int j = 0; j < 4; j++) acc[i][j] = (f32x4)(0.f);

    for (int k0 = 0; k0 < K; k0 += 32) {
        gload16(gA[0] + k0, ldsA[0]);
        gload16(gA[1] + k0, ldsA[1]);
        gload16(gB[0] + k0, ldsB[0]);
        gload16(gB[1] + k0, ldsB[1]);
        __syncthreads();
        short8 af[4], bf[4];
        #pragma unroll
        for (int im = 0; im < 4; ++im) af[im] = *(const short8*)(As + aoff + im * 512);
        #pragma unroll
        for (int in = 0; in < 4; ++in) bf[in] = *(const short8*)(Bs + boff + in * 512);
        #pragma unroll
        for (int im = 0; im < 4; ++im)
            #pragma unroll
            for (int in = 0; in < 4; ++in)
                acc[im][in] = __builtin_amdgcn_mfma_f32_16x16x32_bf16(
                    af[im], bf[in], acc[im][in], 0, 0, 0);
        __syncthreads();
    }

    float bv[4];
    if (EPI == 1 || EPI == 2) {
        #pragma unroll
        for (int in = 0; in < 4; ++in) bv[in] = bias[n0 + wn + in * 16 + (l & 15)];
    }
    #pragma unroll
    for (int im = 0; im < 4; ++im) {
        #pragma unroll
        for (int in = 0; in < 4; ++in) {
            int n = n0 + wn + in * 16 + (l & 15);
            #pragma unroll
            for (int r = 0; r < 4; ++r) {
                int m = m0 + wm + im * 16 + (l >> 4) * 4 + r;
                float v = acc[im][in][r];
                if (EPI == 1) {
                    v = fmaxf(v + bv[in], 0.f);
                    ((unsigned short*)outp)[(size_t)m * N + n] = f2bf(v);
                } else {
                    if (EPI == 2) v += bv[in] + res[(size_t)m * N + n];
                    if (EPI == 3) v += res[(size_t)m * N + n];
                    ((float*)outp)[(size_t)m * N + n] = v;
                }
            }
        }
    }
}

// -------- split-bf16 MFMA GEMM (hi/lo): C = (Ah+Al) @ (Bh+Bl)^T, fp32 out ---
// acc = Ah@Bh + Al@Bh + Ah@Bl  (Al@Bl dropped: ~2^-18 relative)
__global__ __launch_bounds__(256) void gemm_bf16split(
        const unsigned short* __restrict__ Ah, const unsigned short* __restrict__ Al,
        const unsigned short* __restrict__ BTh, const unsigned short* __restrict__ BTl,
        float* __restrict__ outp, int M, int N, int K) {
    __shared__ __align__(16) unsigned short Ash[128 * 32];
    __shared__ __align__(16) unsigned short Asl[128 * 32];
    __shared__ __align__(16) unsigned short Bsh[128 * 32];
    __shared__ __align__(16) unsigned short Bsl[128 * 32];
    int tid = threadIdx.x;
    int w = tid >> 6, l = tid & 63;
    int m0 = blockIdx.y * 128, n0 = blockIdx.x * 128;
    int wm = (w >> 1) * 64, wn = (w & 1) * 64;

    size_t goff[2];
    unsigned short* ldsAh[2]; unsigned short* ldsAl[2];
    unsigned short* ldsBh[2]; unsigned short* ldsBl[2];
    size_t goffB[2];
    int gchunk = (l & 3) ^ ((l >> 3) & 3);
    #pragma unroll
    for (int s = 0; s < 2; ++s) {
        int j = w * 2 + s;
        int R = j * 16 + (l >> 2);
        goff[s]  = (size_t)(m0 + R) * K + gchunk * 8;
        goffB[s] = (size_t)(n0 + R) * K + gchunk * 8;
        ldsAh[s] = Ash + j * 512; ldsAl[s] = Asl + j * 512;
        ldsBh[s] = Bsh + j * 512; ldsBl[s] = Bsl + j * 512;
    }
    int p = (l >> 4) ^ (((l & 15) >> 1) & 3);
    int aoff = (wm + (l & 15)) * 32 + p * 8;
    int boff = (wn + (l & 15)) * 32 + p * 8;

    f32x4 acc[4][4];
    #pragma unroll
    for (int i = 0; i < 4; i++)
        #pragma unroll
        for (int j = 0; j < 4; j++) acc[i][j] = (f32x4)(0.f);

    for (int k0 = 0; k0 < K; k0 += 32) {
        #pragma unroll
        for (int s = 0; s < 2; ++s) {
            gload16(Ah  + goff[s]  + k0, ldsAh[s]);
            gload16(Al  + goff[s]  + k0, ldsAl[s]);
            gload16(BTh + goffB[s] + k0, ldsBh[s]);
            gload16(BTl + goffB[s] + k0, ldsBl[s]);
        }
        __syncthreads();
        short8 afh[4], afl[4], bfh[4], bfl[4];
        #pragma unroll
        for (int im = 0; im < 4; ++im) {
            afh[im] = *(const short8*)(Ash + aoff + im * 512);
            afl[im] = *(const short8*)(Asl + aoff + im * 512);
        }
        #pragma unroll
        for (int in = 0; in < 4; ++in) {
            bfh[in] = *(const short8*)(Bsh + boff + in * 512);
            bfl[in] = *(const short8*)(Bsl + boff + in * 512);
        }
        #pragma unroll
        for (int im = 0; im < 4; ++im)
            #pragma unroll
            for (int in = 0; in < 4; ++in) {
                acc[im][in] = __builtin_amdgcn_mfma_f32_16x16x32_bf16(
                    afh[im], bfh[in], acc[im][in], 0, 0, 0);
                acc[im][in] = __builtin_amdgcn_mfma_f32_16x16x32_bf16(
                    afl[im], bfh[in], acc[im][in], 0, 0, 0);
                acc[im][in] = __builtin_amdgcn_mfma_f32_16x16x32_bf16(
                    afh[im], bfl[in], acc[im][in], 0, 0, 0);
            }
        __syncthreads();
    }

    #pragma unroll
    for (int im = 0; im < 4; ++im)
        #pragma unroll
        for (int in = 0; in < 4; ++in) {
            int n = n0 + wn + in * 16 + (l & 15);
            #pragma unroll
            for (int r = 0; r < 4; ++r) {
                int m = m0 + wm + im * 16 + (l >> 4) * 4 + r;
                outp[(size_t)m * N + n] = acc[im][in][r];
            }
        }
}

// ---------------- fp32 tiled GEMM (rotation + bucket argmax only) -----------
template<int EPI>
__global__ __launch_bounds__(256) void gemm_f32(const float* __restrict__ A,
        const float* __restrict__ W, float* __restrict__ out,
        int M, int N, int K) {
    __shared__ __align__(16) float As[16][132];
    __shared__ __align__(16) float Bs[16][132];
    int tid = threadIdx.x;
    int n0 = blockIdx.x * 128;
    int m0 = blockIdx.y * 128;
    int ty = tid >> 4, tx = tid & 15;
    float acc[8][8];
    #pragma unroll
    for (int i = 0; i < 8; i++)
        #pragma unroll
        for (int j = 0; j < 8; j++) acc[i][j] = 0.f;

    for (int k0 = 0; k0 < K; k0 += 16) {
        #pragma unroll
        for (int it = 0; it < 2; ++it) {
            int f4 = tid + it * 256;
            int row = f4 >> 2, c4 = f4 & 3;
            float4 av = *(const float4*)(A + (size_t)(m0 + row) * K + k0 + c4 * 4);
            As[c4 * 4 + 0][row] = av.x;
            As[c4 * 4 + 1][row] = av.y;
            As[c4 * 4 + 2][row] = av.z;
            As[c4 * 4 + 3][row] = av.w;
        }
        #pragma unroll
        for (int it = 0; it < 2; ++it) {
            int f4 = tid + it * 256;
            int kr = f4 >> 5, c4 = f4 & 31;
            *(float4*)(&Bs[kr][c4 * 4]) =
                *(const float4*)(W + (size_t)(k0 + kr) * N + n0 + c4 * 4);
        }
        __syncthreads();
        #pragma unroll
        for (int kk = 0; kk < 16; ++kk) {
            float4 a0 = *(const float4*)(&As[kk][ty * 8]);
            float4 a1 = *(const float4*)(&As[kk][ty * 8 + 4]);
            float4 b0 = *(const float4*)(&Bs[kk][tx * 8]);
            float4 b1 = *(const float4*)(&Bs[kk][tx * 8 + 4]);
            float am[8] = {a0.x, a0.y, a0.z, a0.w, a1.x, a1.y, a1.z, a1.w};
            float bn[8] = {b0.x, b0.y, b0.z, b0.w, b1.x, b1.y, b1.z, b1.w};
            #pragma unroll
            for (int i = 0; i < 8; i++)
                #pragma unroll
                for (int j = 0; j < 8; j++)
                    acc[i][j] = fmaf(am[i], bn[j], acc[i][j]);
        }
        __syncthreads();
    }

    if (EPI == 4) {
        int* ibuck = (int*)out;
        int q = tx & 3, r = tx >> 2;      // col = r*32 + q*8 + j
        #pragma unroll
        for (int i = 0; i < 8; i++) {
            int m = m0 + ty * 8 + i;
            float bestP = -3.4e38f, bestN = -3.4e38f;
            int biP = 0, biN = 0;
            #pragma unroll
            for (int j = 0; j < 8; j++) {
                float v = acc[i][j];
                if ( v > bestP) { bestP =  v; biP = q * 8 + j; }
                if (-v > bestN) { bestN = -v; biN = q * 8 + j; }
            }
            #pragma unroll
            for (int off = 1; off < 4; off <<= 1) {
                float oP = __shfl_xor(bestP, off); int oiP = __shfl_xor(biP, off);
                float oN = __shfl_xor(bestN, off); int oiN = __shfl_xor(biN, off);
                if (oP > bestP || (oP == bestP && oiP < biP)) { bestP = oP; biP = oiP; }
                if (oN > bestN || (oN == bestN && oiN < biN)) { bestN = oN; biN = oiN; }
            }
            if (q == 0) {
                int bi = (bestP >= bestN) ? biP : (biN + 32);
                int hh = m & 15, ss2 = (m >> 4) & (CS - 1), bb2 = m >> 16;
                ibuck[((size_t)((r * CB + bb2) * CH + hh)) * CS + ss2] = bi;
            }
        }
        return;
    }

    #pragma unroll
    for (int i = 0; i < 8; i++) {
        int m = m0 + ty * 8 + i;
        #pragma unroll
        for (int j4 = 0; j4 < 2; j4++) {
            int n = n0 + tx * 8 + j4 * 4;
            float4 v;
            v.x = acc[i][j4 * 4 + 0]; v.y = acc[i][j4 * 4 + 1];
            v.z = acc[i][j4 * 4 + 2]; v.w = acc[i][j4 * 4 + 3];
            *(float4*)(out + (size_t)m * N + n) = v;
        }
    }
}

// ---------------- stable counting sort per (r,b,h): one wave ----------------
__global__ __launch_bounds__(64) void sort_kernel(const int* __restrict__ buckets,
                                                  int* __restrict__ sorted_pos) {
    int g = blockIdx.x;                  // rbh
    const int* bk = buckets + (size_t)g * CS;
    __shared__ int hist[64][65];
    __shared__ int bstart[64];
    int t = threadIdx.x;
    #pragma unroll
    for (int i = 0; i < 64; i++) hist[t][i] = 0;
    __syncthreads();
    int base = t * 64;
    for (int i = 0; i < 64; i++) { int b = bk[base + i]; hist[t][b]++; }
    __syncthreads();
    int run = 0;
    for (int tt = 0; tt < 64; tt++) {
        int c = hist[tt][t];
        hist[tt][t] = run;
        run += c;
    }
    int x = run;
    #pragma unroll
    for (int off = 1; off < 64; off <<= 1) {
        int y = __shfl_up(x, off);
        if (t >= off) x += y;
    }
    bstart[t] = x - run;
    __syncthreads();
    for (int i = 0; i < 64; i++) {
        int b = bk[base + i];
        int rank = bstart[b] + hist[t][b];
        hist[t][b]++;
        sorted_pos[(size_t)g * CS + rank] = base + i;
    }
}

// ---------------- chunked LSH attention (bf16 MFMA) -------------------------
__global__ __launch_bounds__(256) void attn_kernel(const float* __restrict__ qkbuf,
        const float* __restrict__ vbuf, const int* __restrict__ buckets,
        const int* __restrict__ sorted, unsigned short* __restrict__ o_all,
        float* __restrict__ l_all) {
    int n  = blockIdx.x;
    int r  = blockIdx.y;
    int bh = blockIdx.z;
    int b = bh >> 4, h = bh & 15;
    int rbh = (r * CB + b) * CH + h;
    int tid = threadIdx.x;
    int w = tid >> 6, l = tid & 63;
    int l4 = l & 15, qd = l >> 4;

    __shared__ int pk[128];
    __shared__ int bkk[128];
    __shared__ __align__(16) unsigned short Ks[128 * 72];   // K-hat [kk][d]
    __shared__ __align__(16) unsigned short Ps[64 * 132];   // P [m][kk]
    __shared__ __align__(16) unsigned short VsT[64 * 132];  // V^T [d][kk]

    int prev = (n + CNCH - 1) & (CNCH - 1);
    if (tid < 128) {
        int i = tid & 63;
        int ch = (tid < 64) ? n : prev;
        int p = sorted[(size_t)rbh * CS + ch * CC + i];
        pk[tid] = p;
        bkk[tid] = buckets[(size_t)rbh * CS + p];
    }
    __syncthreads();

    const float* qbase = qkbuf + (size_t)b * CS * CD + h * 64;
    const float* vbase = vbuf  + (size_t)b * CS * CD + h * 64;

    #pragma unroll
    for (int it = 0; it < 8; ++it) {
        int f4 = tid + it * 256;            // 0..2047
        int kk = f4 >> 4, d4 = f4 & 15;
        float4 v = *(const float4*)(qbase + (size_t)pk[kk] * CD + d4 * 4);
        float ss = v.x * v.x + v.y * v.y + v.z * v.z + v.w * v.w;
        ss += __shfl_xor(ss, 1); ss += __shfl_xor(ss, 2);
        ss += __shfl_xor(ss, 4); ss += __shfl_xor(ss, 8);
        float rn = 1.f / (sqrtf(ss) + 1e-6f);
        ushort4 hv;
        hv.x = f2bf(v.x * rn); hv.y = f2bf(v.y * rn);
        hv.z = f2bf(v.z * rn); hv.w = f2bf(v.w * rn);
        *(ushort4*)&Ks[kk * 72 + d4 * 4] = hv;
    }
    #pragma unroll
    for (int it = 0; it < 16; ++it) {
        int kkp = w * 16 + it;              // 0..63 (pair index)
        int r0 = pk[2 * kkp], r1 = pk[2 * kkp + 1];
        float v0 = vbase[(size_t)r0 * CD + l];
        float v1 = vbase[(size_t)r1 * CD + l];
        unsigned int pck = (unsigned int)f2bf(v0) | ((unsigned int)f2bf(v1) << 16);
        *(unsigned int*)&VsT[l * 132 + 2 * kkp] = pck;
    }
    int mstrip = w * 16;
    const float* qptr = qbase + (size_t)pk[mstrip + l4] * CD + qd * 8;
    float4 qa0 = *(const float4*)(qptr);
    float4 qa1 = *(const float4*)(qptr + 4);
    float4 qb0 = *(const float4*)(qptr + 32);
    float4 qb1 = *(const float4*)(qptr + 36);
    short8 afA = pack8(qa0, qa1);
    short8 afB = pack8(qb0, qb1);
    __syncthreads();

    f32x4 sa[8];
    #pragma unroll
    for (int t = 0; t < 8; ++t) sa[t] = (f32x4)(0.f);
    #pragma unroll
    for (int t = 0; t < 8; ++t) {
        const unsigned short* kb = &Ks[(t * 16 + l4) * 72 + qd * 8];
        short8 b0 = *(const short8*)(kb);
        short8 b1 = *(const short8*)(kb + 32);
        sa[t] = __builtin_amdgcn_mfma_f32_16x16x32_bf16(afA, b0, sa[t], 0, 0, 0);
        sa[t] = __builtin_amdgcn_mfma_f32_16x16x32_bf16(afB, b1, sa[t], 0, 0, 0);
    }

    int rowb[4], rowp[4];
    #pragma unroll
    for (int rr = 0; rr < 4; ++rr) {
        int m = mstrip + 4 * qd + rr;
        rowb[rr] = bkk[m]; rowp[rr] = pk[m];
    }
    float mx[4] = {-3.4e38f, -3.4e38f, -3.4e38f, -3.4e38f};
    #pragma unroll
    for (int t = 0; t < 8; ++t) {
        int cb = bkk[t * 16 + l4], cp = pk[t * 16 + l4];
        #pragma unroll
        for (int rr = 0; rr < 4; ++rr) {
            float v = sa[t][rr] * 0.125f;
            if (rowb[rr] != cb) v = -1e9f;
            if (rowp[rr] == cp) v = -1e5f;
            sa[t][rr] = v;
            mx[rr] = fmaxf(mx[rr], v);
        }
    }
    #pragma unroll
    for (int rr = 0; rr < 4; ++rr) {
        mx[rr] = fmaxf(mx[rr], __shfl_xor(mx[rr], 1));
        mx[rr] = fmaxf(mx[rr], __shfl_xor(mx[rr], 2));
        mx[rr] = fmaxf(mx[rr], __shfl_xor(mx[rr], 4));
        mx[rr] = fmaxf(mx[rr], __shfl_xor(mx[rr], 8));
    }
    float sum[4] = {0.f, 0.f, 0.f, 0.f};
    #pragma unroll
    for (int t = 0; t < 8; ++t)
        #pragma unroll
        for (int rr = 0; rr < 4; ++rr) {
            float e = expf(sa[t][rr] - mx[rr]);
            sa[t][rr] = e;
            sum[rr] += e;
        }
    #pragma unroll
    for (int rr = 0; rr < 4; ++rr) {
        sum[rr] += __shfl_xor(sum[rr], 1);
        sum[rr] += __shfl_xor(sum[rr], 2);
        sum[rr] += __shfl_xor(sum[rr], 4);
        sum[rr] += __shfl_xor(sum[rr], 8);
    }
    if (l4 == 0) {
        #pragma unroll
        for (int rr = 0; rr < 4; ++rr)
            l_all[(size_t)rbh * CS + rowp[rr]] = mx[rr] + logf(sum[rr]);
    }

    float rs[4];
    #pragma unroll
    for (int rr = 0; rr < 4; ++rr) rs[rr] = 1.f / sum[rr];
    #pragma unroll
    for (int t = 0; t < 8; ++t)
        #pragma unroll
        for (int rr = 0; rr < 4; ++rr)
            Ps[(mstrip + 4 * qd + rr) * 132 + t * 16 + l4] = f2bf(sa[t][rr] * rs[rr]);

    f32x4 oa[4];
    #pragma unroll
    for (int nt = 0; nt < 4; ++nt) oa[nt] = (f32x4)(0.f);
    #pragma unroll
    for (int ks = 0; ks < 4; ++ks) {
        short8 ap = ld_short8_u(&Ps[(mstrip + l4) * 132 + ks * 32 + qd * 8]);
        #pragma unroll
        for (int nt = 0; nt < 4; ++nt) {
            short8 bv = ld_short8_u(&VsT[(nt * 16 + l4) * 132 + ks * 32 + qd * 8]);
            oa[nt] = __builtin_amdgcn_mfma_f32_16x16x32_bf16(ap, bv, oa[nt], 0, 0, 0);
        }
    }
    #pragma unroll
    for (int nt = 0; nt < 4; ++nt)
        #pragma unroll
        for (int rr = 0; rr < 4; ++rr)
            o_all[((size_t)rbh * CS + rowp[rr]) * CDH + nt * 16 + l4] = f2bf(oa[nt][rr]);
}

// ---------------- combine rounds: softmax over R of logsumexp; bf16 out -----
__global__ __launch_bounds__(256) void combine_kernel(const unsigned short* __restrict__ o_all,
        const float* __restrict__ l_all, unsigned short* __restrict__ attnout16) {
    int idx = blockIdx.x * 256 + threadIdx.x;
    int d = idx & 63, bhs = idx >> 6;
    int s2 = bhs & (CS - 1), bh = bhs >> 12, h = bh & 15, b = bh >> 4;
    float lr[4];
    #pragma unroll
    for (int r = 0; r < CR; r++) lr[r] = l_all[(size_t)r * CBHS + bhs];
    float m = fmaxf(fmaxf(lr[0], lr[1]), fmaxf(lr[2], lr[3]));
    float w[4], sum = 0.f;
    #pragma unroll
    for (int r = 0; r < CR; r++) { w[r] = expf(lr[r] - m); sum += w[r]; }
    float acc = 0.f;
    #pragma unroll
    for (int r = 0; r < CR; r++)
        acc += w[r] * bf2f(o_all[((size_t)r * CBHS + bhs) * CDH + d]);
    acc /= sum;
    attnout16[((size_t)(b * CS + s2)) * CD + h * 64 + d] = f2bf(acc);
}

extern "C" void kernel_launch(void* const* d_in, const int* in_sizes, int n_in,
                              void* d_out, int out_size, void* d_ws, size_t ws_size,
                              hipStream_t stream) {
    const float* x1   = (const float*)d_in[0];
    const float* x2   = (const float*)d_in[1];
    const float* Wqk  = (const float*)d_in[2];
    const float* Wv   = (const float*)d_in[3];
    const float* Wo   = (const float*)d_in[4];
    const float* ln1g = (const float*)d_in[5];
    const float* ln1b = (const float*)d_in[6];
    const float* W1   = (const float*)d_in[7];
    const float* bf1  = (const float*)d_in[8];
    const float* W2   = (const float*)d_in[9];
    const float* bf2  = (const float*)d_in[10];
    const float* ln2g = (const float*)d_in[11];
    const float* ln2b = (const float*)d_in[12];
    const float* rot  = (const float*)d_in[13];   // [64][128] row-major

    unsigned short* bufA16   = (unsigned short*)d_ws;          // ln1 hi bf16
    unsigned short* bufA16lo = bufA16 + (size_t)CBS * CD;      // ln1 lo bf16
    float* bufB = (float*)(bufA16lo + (size_t)CBS * CD);       // qk fp32
    float* bufC = bufB + (size_t)CBS * CD;                     // v fp32
    unsigned short* o_all = (unsigned short*)(bufC + (size_t)CBS * CD);  // bf16
    float* l_all  = (float*)(o_all + (size_t)CR * CBHS * CDH);
    int* buckets  = (int*)(l_all + (size_t)CR * CBHS);
    int* sorted   = buckets + (size_t)CR * CBHS;
    unsigned short* WvT   = (unsigned short*)(sorted + (size_t)CR * CBHS);
    unsigned short* WoT   = WvT + (size_t)CD * CD;
    unsigned short* W1T   = WoT + (size_t)CD * CD;             // [DFF][D]
    unsigned short* W2T   = W1T + (size_t)CD * CDFF;           // [D][DFF]
    unsigned short* WqkTh = W2T + (size_t)CD * CDFF;
    unsigned short* WqkTl = WqkTh + (size_t)CD * CD;
    unsigned short* ffh16 = (unsigned short*)bufB;             // aliases qk+v
    unsigned short* attnout16 = bufA16;                        // reuse (ln1 dead)
    unsigned short* lnY16 = bufA16;                            // reuse again
    float* y1 = (float*)d_out;
    float* y2 = y1 + (size_t)CBS * CD;

    // 0. weight transposes (fp32 -> bf16, [K][N] -> [N][K]); Wqk gets hi+lo
    wtrans_kernel<<<dim3(CD / 64, CD / 64), 256, 0, stream>>>(Wqk, WqkTh, WqkTl, CD, CD);
    wtrans_kernel<<<dim3(CD / 64, CD / 64), 256, 0, stream>>>(Wv, WvT, nullptr, CD, CD);
    wtrans_kernel<<<dim3(CD / 64, CD / 64), 256, 0, stream>>>(Wo, WoT, nullptr, CD, CD);
    wtrans_kernel<<<dim3(CDFF / 64, CD / 64), 256, 0, stream>>>(W1, W1T, nullptr, CD, CDFF);
    wtrans_kernel<<<dim3(CD / 64, CDFF / 64), 256, 0, stream>>>(W2, W2T, nullptr, CDFF, CD);
    // 1. ln(x2) -> bf16 hi + lo
    ln_kernel<<<CBS, 256, 0, stream>>>(x2, ln1g, ln1b, bufA16, bufA16lo);
    // 2. qk projection: split-bf16 MFMA (feeds bucketing; ~fp32 precision)
    gemm_bf16split<<<dim3(CD / 128, CBS / 128), 256, 0, stream>>>(
        bufA16, bufA16lo, WqkTh, WqkTl, bufB, CBS, CD, CD);
    // 3. v projection (bf16 MFMA, fp32 out)
    gemm_bf16<0><<<dim3(CD / 128, CBS / 128), 256, 0, stream>>>(bufA16, WvT, nullptr, nullptr, bufC, CBS, CD, CD);
    // 4. LSH rotation GEMM + fused argmax -> buckets (fp32)
    gemm_f32<4><<<dim3(1, CBHS / 128), 256, 0, stream>>>(bufB, rot, (float*)buckets, CBHS, 128, 64);
    // 5. stable counting sort per (r,b,h)
    sort_kernel<<<CR * CB * CH, 64, 0, stream>>>(buckets, sorted);
    // 6. chunked masked attention (bf16 MFMA)
    attn_kernel<<<dim3(CNCH, CR, CB * CH), 256, 0, stream>>>(bufB, bufC, buckets, sorted, o_all, l_all);
    // 7. round-weighted combine -> attnout bf16
    combine_kernel<<<(CBHS * CDH) / 256, 256, 0, stream>>>(o_all, l_all, attnout16);
    // 8. y1 = attnout @ Wo + x1 (bf16 MFMA, residual epilogue)
    gemm_bf16<3><<<dim3(CD / 128, CBS / 128), 256, 0, stream>>>(attnout16, WoT, nullptr, x1, y1, CBS, CD, CD);
    // 9. ln(y1) -> bf16 only
    ln_kernel<<<CBS, 256, 0, stream>>>(y1, ln2g, ln2b, lnY16, nullptr);
    // 10. ffh = relu(ln_y1 @ W1 + bf1) -> bf16
    gemm_bf16<1><<<dim3(CDFF / 128, CBS / 128), 256, 0, stream>>>(lnY16, W1T, bf1, nullptr, ffh16, CBS, CDFF, CD);
    // 11. y2 = ffh @ W2 + bf2 + x2 (fp32 out)
    gemm_bf16<2><<<dim3(CD / 128, CBS / 128), 256, 0, stream>>>(ffh16, W2T, bf2, x2, y2, CBS, CD, CDFF);
}